// Round 14
// baseline (599.370 us; speedup 1.0000x reference)
//
#include <hip/hip_runtime.h>
#include <hip/hip_bf16.h>

#define PI_F 3.14159265358979323846f

typedef short  bf16x8 __attribute__((ext_vector_type(8)));
typedef unsigned short u16x8 __attribute__((ext_vector_type(8)));
typedef float  f32x4  __attribute__((ext_vector_type(4)));

// ---- ws layout (bytes) ----
#define OUT3_OFF  0                       // [3][1024][257] f32 = 3,158,016 B
#define TPACK_OFF 3158016                 // [128 tiles][64][8] bf16 = 131,072 B

// barrier WITHOUT vmcnt drain: LDS ordering only (in-flight global loads live on)
#define BAR() do { asm volatile("s_waitcnt lgkmcnt(0)" ::: "memory"); \
                   __builtin_amdgcn_s_barrier(); } while (0)

static __device__ __forceinline__ unsigned short f2bf(float x) {
    unsigned int u = __float_as_uint(x);
    unsigned int r = (u + 0x7fffu + ((u >> 16) & 1u)) >> 16;   // RNE
    return (unsigned short)r;
}

static __device__ __forceinline__ float sigm(float x) {
    return 1.f / (1.f + expf(-x));
}

// ------------------------------------------------------------------
// Kernel A: three LinearOutputStacks. 8 rows/block, 512 threads,
// row-half split (rows 0-3 / 4-7). grid (128,3) = 384 blocks.
// ------------------------------------------------------------------

__device__ __forceinline__ void ln512(float (*buf)[256], float* mrow, float* rrow)
{
    const int tid = threadIdx.x;
    const int lane = tid & 63, wv = tid >> 6;      // wave wv reduces row wv
    float s = 0.f, s2 = 0.f;
    #pragma unroll
    for (int j = 0; j < 4; j++) {
        float v = buf[wv][lane + 64*j];
        s += v; s2 += v*v;
    }
    #pragma unroll
    for (int o = 32; o > 0; o >>= 1) {
        s  += __shfl_xor(s,  o, 64);
        s2 += __shfl_xor(s2, o, 64);
    }
    if (lane == 0) {
        float m   = s * (1.f/256.f);
        float var = s2 * (1.f/256.f) - m*m;
        mrow[wv] = m;
        rrow[wv] = rsqrtf(var + 1e-5f);
    }
    __syncthreads();
    #pragma unroll
    for (int idx = tid; idx < 2048; idx += 512) {
        int r = idx >> 8, cc = idx & 255;
        buf[r][cc] = (buf[r][cc] - mrow[r]) * rrow[r];
    }
    __syncthreads();
}

// KDIM -> 256 matmul + bias + leaky_relu(0.2), row-half split
template<int KDIM>
__device__ __forceinline__ void mmvh(const float (*in)[KDIM],
                                     const float* __restrict__ W,
                                     const float* __restrict__ bias,
                                     float (*outb)[256])
{
    const int tid = threadIdx.x;
    const int c  = tid & 255;
    const int r0 = (tid >> 8) * 4;
    float acc[4] = {0.f, 0.f, 0.f, 0.f};
    const float* Wp = W + c;
    for (int l16 = 0; l16 < KDIM; l16 += 16) {
        float wbuf[16];
        #pragma unroll
        for (int j = 0; j < 16; j++) wbuf[j] = Wp[(size_t)(l16 + j)*256];
        #pragma unroll
        for (int q = 0; q < 4; q++) {
            f32x4 iq[4];
            #pragma unroll
            for (int r = 0; r < 4; r++) iq[r] = *(const f32x4*)&in[r0 + r][l16 + q*4];
            #pragma unroll
            for (int jj = 0; jj < 4; jj++)
                #pragma unroll
                for (int r = 0; r < 4; r++)
                    acc[r] = fmaf(iq[r][jj], wbuf[q*4 + jj], acc[r]);
        }
    }
    const float bb = bias[c];
    #pragma unroll
    for (int r = 0; r < 4; r++) {
        float v = acc[r] + bb;
        outb[r0 + r][c] = (v >= 0.f) ? v : 0.2f*v;
    }
}

__global__ __launch_bounds__(512) void mlp_kernel(
    const float* __restrict__ latents,
    const float* __restrict__ Win,  const float* __restrict__ b_in,
    const float* __restrict__ Wh,   const float* __restrict__ b_h,
    const float* __restrict__ Wout, const float* __restrict__ b_out,
    float* __restrict__ out3)
{
    __shared__ float bufA[8][128];
    __shared__ float bufB[8][256];
    __shared__ float bufC[8][256];
    __shared__ float mrow[8], rrow[8];

    const int tid  = threadIdx.x;
    const int s    = blockIdx.y;
    const int row0 = blockIdx.x * 8;
    const int c    = tid & 255;
    const int r0   = (tid >> 8) * 4;

    for (int idx = tid; idx < 8*128; idx += 512) {
        int r = idx >> 7, l = idx & 127;
        bufA[r][l] = latents[(size_t)(row0 + r)*128 + l];
    }
    __syncthreads();

    mmvh<128>(bufA, Win + (size_t)s*128*256, b_in + s*256, bufB);
    __syncthreads();
    ln512(bufB, mrow, rrow);

    mmvh<256>(bufB, Wh + ((size_t)s*2 + 0)*256*256, b_h + (s*2 + 0)*256, bufC);
    __syncthreads();
    ln512(bufC, mrow, rrow);

    mmvh<256>(bufC, Wh + ((size_t)s*2 + 1)*256*256, b_h + (s*2 + 1)*256, bufB);
    __syncthreads();
    ln512(bufB, mrow, rrow);

    // output layer: 256 -> 257 (+bias), raw
    {
        float acc[4] = {0.f, 0.f, 0.f, 0.f};
        const float* Wp = Wout + (size_t)s*256*257 + c;
        for (int l16 = 0; l16 < 256; l16 += 16) {
            float wbuf[16];
            #pragma unroll
            for (int j = 0; j < 16; j++) wbuf[j] = Wp[(size_t)(l16 + j)*257];
            #pragma unroll
            for (int q = 0; q < 4; q++) {
                f32x4 iq[4];
                #pragma unroll
                for (int r = 0; r < 4; r++) iq[r] = *(const f32x4*)&bufB[r0 + r][l16 + q*4];
                #pragma unroll
                for (int jj = 0; jj < 4; jj++)
                    #pragma unroll
                    for (int r = 0; r < 4; r++)
                        acc[r] = fmaf(iq[r][jj], wbuf[q*4 + jj], acc[r]);
            }
        }
        float bb = b_out[s*257 + c];
        #pragma unroll
        for (int r = 0; r < 4; r++)
            out3[((size_t)s*1024 + row0 + r0 + r)*257 + c] = acc[r] + bb;

        // column 256 (one thread per row)
        if (tid < 8) {
            const int r = tid;
            float a = 0.f;
            const float* Wp2 = Wout + (size_t)s*256*257 + 256;
            for (int l = 0; l < 256; ++l)
                a = fmaf(bufB[r][l], Wp2[(size_t)l*257], a);
            out3[((size_t)s*1024 + row0 + r)*257 + 256] = a + b_out[s*257 + 256];
        }
    }
}

// ------------------------------------------------------------------
// K1: pack the half-spectrum iDFT basis (k-mirror + w-parity split).
// kappa = k2/2 + 1 in [1,128];  row k2 even -> cos(2pi kappa w/512),
// odd -> sin.  tile = ks*16 + wg*2 + p;  128 tiles x 1 KB = 128 KB.
// ------------------------------------------------------------------
__global__ __launch_bounds__(256) void tpack_init(unsigned short* __restrict__ tp)
{
    int g = blockIdx.x * 256 + threadIdx.x;      // 128*64 = 8192 threads exactly
    int tile = g >> 6, l = g & 63;
    int ks = tile >> 4;                          // 0..7
    int wg = (tile >> 1) & 7;                    // 0..7
    int p  = tile & 1;                           // parity
    u16x8 v;
    #pragma unroll
    for (int j = 0; j < 8; ++j) {
        int k2 = ks*32 + ((l >> 4) << 3) + j;    // < 256
        int kap = (k2 >> 1) + 1;                 // 1..128
        int w  = wg*32 + 2*(l & 15) + p;         // < 256
        int m  = (kap * w) & 511;                // exact angle reduction
        float ang = (float)m * (PI_F / 256.f);
        float sn, cn; sincosf(ang, &sn, &cn);
        v[j] = f2bf((k2 & 1) ? sn : cn);
    }
    *(u16x8*)(tp + (size_t)g * 8) = v;
}

// ------------------------------------------------------------------
// K2: full-row fused scan + half-K MFMA iDFT + Hann/OLA.
// grid 1024, block 512 (8 waves), __launch_bounds__(512,4): 2 blocks/CU.
// THIS ROUND: noise loads are software-pipelined one 8-frame group ahead,
// and all in-loop barriers are raw s_barrier + lgkmcnt(0) only (no vmcnt
// drain) so prefetch loads stay in flight across barriers (T4 idiom).
// Every cross-thread dependency in the loop is LDS -> lgkmcnt(0) suffices.
// ------------------------------------------------------------------
__global__ __launch_bounds__(512, 4) void synth_row(
    const float* __restrict__ out3,
    const float* __restrict__ phase0_u,
    const float* __restrict__ noise_u,
    const unsigned short* __restrict__ tpack,
    float* __restrict__ out)
{
    __shared__ __align__(16) unsigned int lds_u[16896];   // 67,584 B union
    __shared__ float a0s[64];
    __shared__ float a256s[64];
    __shared__ float pbuf[8][260];                        // 8,320 B

    unsigned int* abtP = lds_u;                  // [64][132] u32
    unsigned int* abtQ = lds_u + 64*132;         // [64][132] u32
    float*        xbf  = (float*)lds_u;          // [32][516] f32

    const int tid = threadIdx.x;
    const int row = blockIdx.x;
    const int b   = row >> 9;
    const int e   = row & 511;

    const float inv = 0.04419417382415922f;      // 1/sqrt(512)

    // ---- producer init (tid <= 256): phase recurrence only ----
    float pr = 0.f, dith_ = 0.f, gdd = 0.f;
    if (tid <= 256) {
        float dpre = out3[((size_t)2*1024 + row)*257 + tid];
        dith_ = sigm(dpre);
        float gd = (float)tid * (1.f/512.f);
        gdd = gd - 0.5f*dith_;                   // pr += fma(dith, nz, gdd)
        pr  = phase0_u[(size_t)row*257 + tid] - 0.5f;
    }
    // thread 256: Nyquist-bin evaluation state
    float m2 = 0.f, res2_ = 0.f;
    if (tid == 256) {
        float i2 = out3[((size_t)0*1024 + row)*257 + 256];
        float r2 = out3[((size_t)1*1024 + row)*257 + 256];
        res2_ = 0.5f + 0.4995f * sigm(r2);
        m2    = inv * i2;
    }

    // ---- consumer init (all threads): bin kc, frames j0..j0+3 ----
    const int kc = tid & 255;
    const int j0 = (tid >> 8) * 4;               // 0 or 4
    float m_base, rp1, rp2, rp3, res8;
    float bsgn = -1.f;
    unsigned int* tgt = abtP;                    // kc==0 never writes tgt
    {
        float ini  = out3[((size_t)0*1024 + row)*257 + kc];
        float rpre = out3[((size_t)1*1024 + row)*257 + kc];
        float res  = 0.5f + 0.4995f * sigm(rpre);
        float cs   = (kc == 0 ? 1.f : 2.f) * inv;
        rp1 = res;
        rp2 = res * res;
        rp3 = rp2 * res;
        float res4 = rp2 * rp2;
        res8 = res4 * res4;
        m_base = cs * ini;
        if (j0 == 4) m_base *= res4;
        if (kc >= 129)     { tgt = abtQ + (255 - kc); bsgn = 1.f; }
        else if (kc >= 1)  { tgt = abtP + (kc - 1); }
    }

    const float* nrow = noise_u + ((size_t)b*128*512 + e)*257;
    const size_t nstride = (size_t)512*257;

    // OLA constants for col w = tid (threads < 256)
    float h1 = 0.f, h2 = 0.f;
    {
        float c0 = __builtin_amdgcn_cosf((float)tid * (1.f/512.f));
        h1 = 0.5f - 0.5f*c0;                     // hann[tid]
        h2 = 0.5f + 0.5f*c0;                     // hann[tid+256]
    }
    const float sgn = (tid & 1) ? -1.f : 1.f;    // (-1)^w
    float tail = 0.f;

    const int l  = tid & 63;
    const int wv = tid >> 6;                     // 0..7: 32-col slice
    const int m0 = l & 15;
    const int ac = l >> 4;
    const int4* abtP4 = (const int4*)abtP;       // row stride 33 int4
    const int4* abtQ4 = (const int4*)abtQ;
    const int4* Tp    = (const int4*)tpack;
    const unsigned int S = 0x80008000u;

    // ---- prologue: preload noise for sweep 0, group 0 ----
    float nzb[8];
    if (tid <= 256) {
        #pragma unroll
        for (int j = 0; j < 8; ++j)
            nzb[j] = (j >= 1) ? __builtin_nontemporal_load(
                                    &nrow[(size_t)j*nstride + tid]) : 0.5f;
    }

    for (int sweep = 0; sweep < 2; ++sweep) {
        const int F0 = sweep * 64;

        // ---- phase 1: pipelined producer/consumer scan, 8 groups ----
        for (int g = 0; g < 8; ++g) {
            if (tid <= 256) {
                // consume current group's noise -> phase cumsum
                #pragma unroll
                for (int j = 0; j < 8; ++j) {
                    int t = F0 + g*8 + j;
                    if (t >= 1) pr += fmaf(dith_, nzb[j], gdd);
                    pbuf[j][tid] = pr;
                    if (tid == 256) {            // Nyquist: cos only
                        if (t >= 1) m2 *= res2_;
                        float fr = pr - floorf(pr);
                        a256s[g*8 + j] = m2 * __builtin_amdgcn_cosf(fr);
                    }
                }
                // prefetch NEXT group's 8 frames (stays in flight across
                // the consumer eval and, at g=7, across GEMM+epilogue)
                {
                    const int tb = F0 + g*8 + 8;
                    #pragma unroll
                    for (int j = 0; j < 8; ++j) {
                        int t = tb + j;
                        nzb[j] = (t < 128) ? __builtin_nontemporal_load(
                                     &nrow[(size_t)t*nstride + tid]) : 0.5f;
                    }
                }
            } else if (g == 0 && tid >= 448) {
                // zero abtQ kappa=128 column (clobbered by xbf each sweep)
                abtQ[(tid - 448)*132 + 127] = 0;
            }
            BAR();

            // consumers: all 512 threads, 4 (bin,frame) items each
            {
                const int fb = g*8 + j0;
                float mv[4];
                mv[0] = m_base;
                mv[1] = m_base * rp1;
                mv[2] = m_base * rp2;
                mv[3] = m_base * rp3;
                #pragma unroll
                for (int q = 0; q < 4; ++q) {
                    float p  = pbuf[j0 + q][kc];
                    float fr = p - floorf(p);
                    float sn = __builtin_amdgcn_sinf(fr);
                    float cn = __builtin_amdgcn_cosf(fr);
                    float a  = mv[q] * cn;
                    if (kc == 0) {
                        a0s[fb + q] = a;
                    } else {
                        float bv = bsgn * mv[q] * sn;
                        tgt[(fb + q)*132] =
                            (unsigned int)f2bf(a) | ((unsigned int)f2bf(bv) << 16);
                    }
                }
                m_base *= res8;
            }
            BAR();
        }

        // ---- phase 2: MFMA  M=64, N=256 (parity-split), K=256 ----
        f32x4 accE[4], accO[4], accER[4], accOR[4];
        #pragma unroll
        for (int mt = 0; mt < 4; ++mt) {
            accE[mt]  = (f32x4){0.f, 0.f, 0.f, 0.f};
            accO[mt]  = (f32x4){0.f, 0.f, 0.f, 0.f};
            accER[mt] = (f32x4){0.f, 0.f, 0.f, 0.f};
            accOR[mt] = (f32x4){0.f, 0.f, 0.f, 0.f};
        }
        {
            const int r0g = m0*33 + ac;
            for (int ks = 0; ks < 8; ++ks) {
                const int4* tb = Tp + (size_t)((ks*16 + wv*2) << 6) + l;
                int4 be = tb[0];
                int4 bo = tb[64];
                bf16x8 BE = *(bf16x8*)&be;
                bf16x8 BO = *(bf16x8*)&bo;
                #pragma unroll
                for (int mt = 0; mt < 4; ++mt) {
                    int4 ap = abtP4[r0g + mt*528 + ks*4];
                    int4 aq = abtQ4[r0g + mt*528 + ks*4];
                    int4 apf = ap;  apf.x ^= S;  apf.z ^= S;      // flip odd kappa
                    int4 aqf = aq;  aqf.x ^= S;  aqf.z ^= S;
                    int4 aqn = aq;  aqn.x ^= S;  aqn.y ^= S;  aqn.z ^= S;  aqn.w ^= S;
                    int4 aqnf = aq; aqnf.y ^= S; aqnf.w ^= S;     // negate(flip)
                    bf16x8 AP   = *(bf16x8*)&ap;
                    bf16x8 APF  = *(bf16x8*)&apf;
                    bf16x8 AQ   = *(bf16x8*)&aq;
                    bf16x8 AQF  = *(bf16x8*)&aqf;
                    bf16x8 AQN  = *(bf16x8*)&aqn;
                    bf16x8 AQNF = *(bf16x8*)&aqnf;
                    accE[mt]  = __builtin_amdgcn_mfma_f32_16x16x32_bf16(AP,   BE, accE[mt],  0, 0, 0);
                    accE[mt]  = __builtin_amdgcn_mfma_f32_16x16x32_bf16(AQ,   BE, accE[mt],  0, 0, 0);
                    accO[mt]  = __builtin_amdgcn_mfma_f32_16x16x32_bf16(AP,   BO, accO[mt],  0, 0, 0);
                    accO[mt]  = __builtin_amdgcn_mfma_f32_16x16x32_bf16(AQN,  BO, accO[mt],  0, 0, 0);
                    accER[mt] = __builtin_amdgcn_mfma_f32_16x16x32_bf16(APF,  BE, accER[mt], 0, 0, 0);
                    accER[mt] = __builtin_amdgcn_mfma_f32_16x16x32_bf16(AQF,  BE, accER[mt], 0, 0, 0);
                    accOR[mt] = __builtin_amdgcn_mfma_f32_16x16x32_bf16(APF,  BO, accOR[mt], 0, 0, 0);
                    accOR[mt] = __builtin_amdgcn_mfma_f32_16x16x32_bf16(AQNF, BO, accOR[mt], 0, 0, 0);
                }
            }
        }
        BAR();   // abt ds-reads done; xbf may overwrite

        // ---- phase 3: two 32-frame halves: acc -> xbf -> Hann+OLA ----
        #pragma unroll
        for (int h = 0; h < 2; ++h) {
            #pragma unroll
            for (int mt2 = 0; mt2 < 2; ++mt2) {
                int mtg = 2*h + mt2;
                int colE = wv*32 + 2*m0;
                #pragma unroll
                for (int r = 0; r < 4; ++r) {
                    int f_loc = mt2*16 + ac*4 + r;
                    float2 vL = make_float2(accE[mtg][r],  accO[mtg][r]);
                    float2 vR = make_float2(accER[mtg][r], accOR[mtg][r]);
                    *(float2*)&xbf[f_loc*516 + colE      ] = vL;
                    *(float2*)&xbf[f_loc*516 + colE + 256] = vR;
                }
            }
            BAR();
            if (tid < 256) {
                float* orow = out + (size_t)row*32768 + (size_t)(F0 + h*32)*256 + tid;
                #pragma unroll
                for (int f = 0; f < 32; ++f) {
                    int hf = h*32 + f;
                    float s  = a0s[hf] + sgn * a256s[hf];
                    float x1 = xbf[f*516 + tid] + s;
                    float x2 = xbf[f*516 + tid + 256] + s;
                    float v  = fmaf(x1, h1, tail);
                    tail = x2 * h2;
                    __builtin_nontemporal_store(v, &orow[f*256]);
                }
            }
            BAR();   // xbf reads done before next write / next sweep's scan
        }
    }
}

// ------------------------------------------------------------------

extern "C" void kernel_launch(void* const* d_in, const int* in_sizes, int n_in,
                              void* d_out, int out_size, void* d_ws, size_t ws_size,
                              hipStream_t stream)
{
    const float* latents  = (const float*)d_in[0];
    const float* phase0_u = (const float*)d_in[1];
    const float* noise_u  = (const float*)d_in[2];
    const float* Win      = (const float*)d_in[3];
    const float* b_in     = (const float*)d_in[4];
    const float* Wh       = (const float*)d_in[5];
    const float* b_h      = (const float*)d_in[6];
    const float* Wout     = (const float*)d_in[7];
    const float* b_out    = (const float*)d_in[8];

    unsigned char* ws = (unsigned char*)d_ws;
    float*          out3  = (float*)(ws + OUT3_OFF);
    unsigned short* tpack = (unsigned short*)(ws + TPACK_OFF);
    float*          out   = (float*)d_out;

    dim3 gA(128, 3);
    mlp_kernel<<<gA, 512, 0, stream>>>(latents, Win, b_in, Wh, b_h, Wout, b_out, out3);
    tpack_init<<<32, 256, 0, stream>>>(tpack);
    synth_row<<<1024, 512, 0, stream>>>(out3, phase0_u, noise_u, tpack, out);
}

// Round 15
// 236.536 us; speedup vs baseline: 2.5339x; 2.5339x over previous
//
#include <hip/hip_runtime.h>
#include <hip/hip_bf16.h>

#define PI_F 3.14159265358979323846f

typedef short  bf16x8 __attribute__((ext_vector_type(8)));
typedef unsigned short u16x8 __attribute__((ext_vector_type(8)));
typedef float  f32x4  __attribute__((ext_vector_type(4)));

// ---- ws layout (bytes) ----
#define OUT3_OFF  0                       // [3][1024][257] f32 = 3,158,016 B
#define TPACK_OFF 3158016                 // [128 tiles][64][8] bf16 = 131,072 B

static __device__ __forceinline__ unsigned short f2bf(float x) {
    unsigned int u = __float_as_uint(x);
    unsigned int r = (u + 0x7fffu + ((u >> 16) & 1u)) >> 16;   // RNE
    return (unsigned short)r;
}

static __device__ __forceinline__ float sigm(float x) {
    return 1.f / (1.f + expf(-x));
}

// ------------------------------------------------------------------
// Kernel A: three LinearOutputStacks. 8 rows/block, 512 threads,
// row-half split (rows 0-3 / 4-7). grid (128,3) = 384 blocks.
// ------------------------------------------------------------------

__device__ __forceinline__ void ln512(float (*buf)[256], float* mrow, float* rrow)
{
    const int tid = threadIdx.x;
    const int lane = tid & 63, wv = tid >> 6;      // wave wv reduces row wv
    float s = 0.f, s2 = 0.f;
    #pragma unroll
    for (int j = 0; j < 4; j++) {
        float v = buf[wv][lane + 64*j];
        s += v; s2 += v*v;
    }
    #pragma unroll
    for (int o = 32; o > 0; o >>= 1) {
        s  += __shfl_xor(s,  o, 64);
        s2 += __shfl_xor(s2, o, 64);
    }
    if (lane == 0) {
        float m   = s * (1.f/256.f);
        float var = s2 * (1.f/256.f) - m*m;
        mrow[wv] = m;
        rrow[wv] = rsqrtf(var + 1e-5f);
    }
    __syncthreads();
    #pragma unroll
    for (int idx = tid; idx < 2048; idx += 512) {
        int r = idx >> 8, cc = idx & 255;
        buf[r][cc] = (buf[r][cc] - mrow[r]) * rrow[r];
    }
    __syncthreads();
}

// KDIM -> 256 matmul + bias + leaky_relu(0.2), row-half split
template<int KDIM>
__device__ __forceinline__ void mmvh(const float (*in)[KDIM],
                                     const float* __restrict__ W,
                                     const float* __restrict__ bias,
                                     float (*outb)[256])
{
    const int tid = threadIdx.x;
    const int c  = tid & 255;
    const int r0 = (tid >> 8) * 4;
    float acc[4] = {0.f, 0.f, 0.f, 0.f};
    const float* Wp = W + c;
    for (int l16 = 0; l16 < KDIM; l16 += 16) {
        float wbuf[16];
        #pragma unroll
        for (int j = 0; j < 16; j++) wbuf[j] = Wp[(size_t)(l16 + j)*256];
        #pragma unroll
        for (int q = 0; q < 4; q++) {
            f32x4 iq[4];
            #pragma unroll
            for (int r = 0; r < 4; r++) iq[r] = *(const f32x4*)&in[r0 + r][l16 + q*4];
            #pragma unroll
            for (int jj = 0; jj < 4; jj++)
                #pragma unroll
                for (int r = 0; r < 4; r++)
                    acc[r] = fmaf(iq[r][jj], wbuf[q*4 + jj], acc[r]);
        }
    }
    const float bb = bias[c];
    #pragma unroll
    for (int r = 0; r < 4; r++) {
        float v = acc[r] + bb;
        outb[r0 + r][c] = (v >= 0.f) ? v : 0.2f*v;
    }
}

__global__ __launch_bounds__(512) void mlp_kernel(
    const float* __restrict__ latents,
    const float* __restrict__ Win,  const float* __restrict__ b_in,
    const float* __restrict__ Wh,   const float* __restrict__ b_h,
    const float* __restrict__ Wout, const float* __restrict__ b_out,
    float* __restrict__ out3)
{
    __shared__ float bufA[8][128];
    __shared__ float bufB[8][256];
    __shared__ float bufC[8][256];
    __shared__ float mrow[8], rrow[8];

    const int tid  = threadIdx.x;
    const int s    = blockIdx.y;
    const int row0 = blockIdx.x * 8;
    const int c    = tid & 255;
    const int r0   = (tid >> 8) * 4;

    for (int idx = tid; idx < 8*128; idx += 512) {
        int r = idx >> 7, l = idx & 127;
        bufA[r][l] = latents[(size_t)(row0 + r)*128 + l];
    }
    __syncthreads();

    mmvh<128>(bufA, Win + (size_t)s*128*256, b_in + s*256, bufB);
    __syncthreads();
    ln512(bufB, mrow, rrow);

    mmvh<256>(bufB, Wh + ((size_t)s*2 + 0)*256*256, b_h + (s*2 + 0)*256, bufC);
    __syncthreads();
    ln512(bufC, mrow, rrow);

    mmvh<256>(bufC, Wh + ((size_t)s*2 + 1)*256*256, b_h + (s*2 + 1)*256, bufB);
    __syncthreads();
    ln512(bufB, mrow, rrow);

    // output layer: 256 -> 257 (+bias), raw
    {
        float acc[4] = {0.f, 0.f, 0.f, 0.f};
        const float* Wp = Wout + (size_t)s*256*257 + c;
        for (int l16 = 0; l16 < 256; l16 += 16) {
            float wbuf[16];
            #pragma unroll
            for (int j = 0; j < 16; j++) wbuf[j] = Wp[(size_t)(l16 + j)*257];
            #pragma unroll
            for (int q = 0; q < 4; q++) {
                f32x4 iq[4];
                #pragma unroll
                for (int r = 0; r < 4; r++) iq[r] = *(const f32x4*)&bufB[r0 + r][l16 + q*4];
                #pragma unroll
                for (int jj = 0; jj < 4; jj++)
                    #pragma unroll
                    for (int r = 0; r < 4; r++)
                        acc[r] = fmaf(iq[r][jj], wbuf[q*4 + jj], acc[r]);
            }
        }
        float bb = b_out[s*257 + c];
        #pragma unroll
        for (int r = 0; r < 4; r++)
            out3[((size_t)s*1024 + row0 + r0 + r)*257 + c] = acc[r] + bb;

        // column 256 (one thread per row)
        if (tid < 8) {
            const int r = tid;
            float a = 0.f;
            const float* Wp2 = Wout + (size_t)s*256*257 + 256;
            for (int l = 0; l < 256; ++l)
                a = fmaf(bufB[r][l], Wp2[(size_t)l*257], a);
            out3[((size_t)s*1024 + row0 + r)*257 + 256] = a + b_out[s*257 + 256];
        }
    }
}

// ------------------------------------------------------------------
// K1: pack the half-spectrum iDFT basis (k-mirror + w-parity split).
// kappa = k2/2 + 1 in [1,128];  row k2 even -> cos(2pi kappa w/512),
// odd -> sin.  tile = ks*16 + wg*2 + p;  128 tiles x 1 KB = 128 KB.
// ------------------------------------------------------------------
__global__ __launch_bounds__(256) void tpack_init(unsigned short* __restrict__ tp)
{
    int g = blockIdx.x * 256 + threadIdx.x;      // 128*64 = 8192 threads exactly
    int tile = g >> 6, l = g & 63;
    int ks = tile >> 4;                          // 0..7
    int wg = (tile >> 1) & 7;                    // 0..7
    int p  = tile & 1;                           // parity
    u16x8 v;
    #pragma unroll
    for (int j = 0; j < 8; ++j) {
        int k2 = ks*32 + ((l >> 4) << 3) + j;    // < 256
        int kap = (k2 >> 1) + 1;                 // 1..128
        int w  = wg*32 + 2*(l & 15) + p;         // < 256
        int m  = (kap * w) & 511;                // exact angle reduction
        float ang = (float)m * (PI_F / 256.f);
        float sn, cn; sincosf(ang, &sn, &cn);
        v[j] = f2bf((k2 & 1) ? sn : cn);
    }
    *(u16x8*)(tp + (size_t)g * 8) = v;
}

// ------------------------------------------------------------------
// K2: full-row fused scan + half-K MFMA iDFT + Hann/OLA.
// grid 1024, block 512 (8 waves), __launch_bounds__(512,4): 2 blocks/CU.
// Base = round-13 (plain __syncthreads; no asm barriers; no reg prefetch).
// NEW: epilogue is parallel in f across ALL 512 threads (out[t] =
// h1*x1[t] + h2*x2[t-1] is not a recurrence); cross-half frame-31 R-half
// (+DC/Nyquist term) carried in LDS carry[256] (read+written by the same
// thread -> ordered by the existing barriers).
// ------------------------------------------------------------------
__global__ __launch_bounds__(512, 4) void synth_row(
    const float* __restrict__ out3,
    const float* __restrict__ phase0_u,
    const float* __restrict__ noise_u,
    const unsigned short* __restrict__ tpack,
    float* __restrict__ out)
{
    __shared__ __align__(16) unsigned int lds_u[16896];   // 67,584 B union
    __shared__ float a0s[64];
    __shared__ float a256s[64];
    __shared__ float pbuf[8][260];                        // 8,320 B
    __shared__ float carry[256];                          // 1,024 B

    unsigned int* abtP = lds_u;                  // [64][132] u32
    unsigned int* abtQ = lds_u + 64*132;         // [64][132] u32
    float*        xbf  = (float*)lds_u;          // [32][516] f32

    const int tid = threadIdx.x;
    const int row = blockIdx.x;
    const int b   = row >> 9;
    const int e   = row & 511;

    const float inv = 0.04419417382415922f;      // 1/sqrt(512)

    // ---- producer init (tid <= 256): phase recurrence only ----
    float pr = 0.f, dith_ = 0.f, gdd = 0.f;
    if (tid <= 256) {
        float dpre = out3[((size_t)2*1024 + row)*257 + tid];
        dith_ = sigm(dpre);
        float gd = (float)tid * (1.f/512.f);
        gdd = gd - 0.5f*dith_;                   // pr += fma(dith, nz, gdd)
        pr  = phase0_u[(size_t)row*257 + tid] - 0.5f;
    }
    // thread 256: Nyquist-bin evaluation state
    float m2 = 0.f, res2_ = 0.f;
    if (tid == 256) {
        float i2 = out3[((size_t)0*1024 + row)*257 + 256];
        float r2 = out3[((size_t)1*1024 + row)*257 + 256];
        res2_ = 0.5f + 0.4995f * sigm(r2);
        m2    = inv * i2;
    }

    // ---- consumer init (all threads): bin kc, frames j0..j0+3 ----
    const int kc = tid & 255;
    const int j0 = (tid >> 8) * 4;               // 0 or 4
    float m_base, rp1, rp2, rp3, res8;
    float bsgn = -1.f;
    unsigned int* tgt = abtP;                    // kc==0 never writes tgt
    {
        float ini  = out3[((size_t)0*1024 + row)*257 + kc];
        float rpre = out3[((size_t)1*1024 + row)*257 + kc];
        float res  = 0.5f + 0.4995f * sigm(rpre);
        float cs   = (kc == 0 ? 1.f : 2.f) * inv;
        rp1 = res;
        rp2 = res * res;
        rp3 = rp2 * res;
        float res4 = rp2 * rp2;
        res8 = res4 * res4;
        m_base = cs * ini;
        if (j0 == 4) m_base *= res4;
        if (kc >= 129)     { tgt = abtQ + (255 - kc); bsgn = 1.f; }
        else if (kc >= 1)  { tgt = abtP + (kc - 1); }
    }

    const float* nrow = noise_u + ((size_t)b*128*512 + e)*257;
    const size_t nstride = (size_t)512*257;

    // OLA constants for output column wE = tid & 255 (both thread-halves)
    const int wE  = tid & 255;
    const int fbE = (tid >> 8) * 16;             // frame sub-half 0..15 / 16..31
    float h1, h2;
    {
        float c0 = __builtin_amdgcn_cosf((float)wE * (1.f/512.f));
        h1 = 0.5f - 0.5f*c0;                     // hann[wE]
        h2 = 0.5f + 0.5f*c0;                     // hann[wE+256]
    }
    const float sgn = (wE & 1) ? -1.f : 1.f;     // (-1)^w
    if (tid < 256) carry[tid] = 0.f;             // no tail before frame 0

    const int l  = tid & 63;
    const int wv = tid >> 6;                     // 0..7: 32-col slice
    const int m0 = l & 15;
    const int ac = l >> 4;
    const int4* abtP4 = (const int4*)abtP;       // row stride 33 int4
    const int4* abtQ4 = (const int4*)abtQ;
    const int4* Tp    = (const int4*)tpack;
    const unsigned int S = 0x80008000u;

    for (int sweep = 0; sweep < 2; ++sweep) {
        const int F0 = sweep * 64;

        // ---- phase 1: producer/consumer scan, 8 groups of 8 frames ----
        for (int g = 0; g < 8; ++g) {
            if (tid <= 256) {
                float nzb[8];
                #pragma unroll
                for (int j = 0; j < 8; ++j) {
                    int t = F0 + g*8 + j;
                    nzb[j] = (t >= 1) ? __builtin_nontemporal_load(
                                            &nrow[(size_t)t*nstride + tid]) : 0.5f;
                }
                #pragma unroll
                for (int j = 0; j < 8; ++j) {
                    int t = F0 + g*8 + j;
                    if (t >= 1) pr += fmaf(dith_, nzb[j], gdd);
                    pbuf[j][tid] = pr;
                    if (tid == 256) {            // Nyquist: cos only
                        if (t >= 1) m2 *= res2_;
                        float fr = pr - floorf(pr);
                        a256s[g*8 + j] = m2 * __builtin_amdgcn_cosf(fr);
                    }
                }
            } else if (g == 0 && tid >= 448) {
                // zero abtQ kappa=128 column (clobbered by xbf each sweep)
                abtQ[(tid - 448)*132 + 127] = 0;
            }
            __syncthreads();

            // consumers: all 512 threads, 4 (bin,frame) items each
            {
                const int fb = g*8 + j0;
                float mv[4];
                mv[0] = m_base;
                mv[1] = m_base * rp1;
                mv[2] = m_base * rp2;
                mv[3] = m_base * rp3;
                #pragma unroll
                for (int q = 0; q < 4; ++q) {
                    float p  = pbuf[j0 + q][kc];
                    float fr = p - floorf(p);
                    float sn = __builtin_amdgcn_sinf(fr);
                    float cn = __builtin_amdgcn_cosf(fr);
                    float a  = mv[q] * cn;
                    if (kc == 0) {
                        a0s[fb + q] = a;
                    } else {
                        float bv = bsgn * mv[q] * sn;
                        tgt[(fb + q)*132] =
                            (unsigned int)f2bf(a) | ((unsigned int)f2bf(bv) << 16);
                    }
                }
                m_base *= res8;
            }
            __syncthreads();
        }

        // ---- phase 2: MFMA  M=64, N=256 (parity-split), K=256 ----
        f32x4 accE[4], accO[4], accER[4], accOR[4];
        #pragma unroll
        for (int mt = 0; mt < 4; ++mt) {
            accE[mt]  = (f32x4){0.f, 0.f, 0.f, 0.f};
            accO[mt]  = (f32x4){0.f, 0.f, 0.f, 0.f};
            accER[mt] = (f32x4){0.f, 0.f, 0.f, 0.f};
            accOR[mt] = (f32x4){0.f, 0.f, 0.f, 0.f};
        }
        {
            const int r0g = m0*33 + ac;
            for (int ks = 0; ks < 8; ++ks) {
                const int4* tb = Tp + (size_t)((ks*16 + wv*2) << 6) + l;
                int4 be = tb[0];
                int4 bo = tb[64];
                bf16x8 BE = *(bf16x8*)&be;
                bf16x8 BO = *(bf16x8*)&bo;
                #pragma unroll
                for (int mt = 0; mt < 4; ++mt) {
                    int4 ap = abtP4[r0g + mt*528 + ks*4];
                    int4 aq = abtQ4[r0g + mt*528 + ks*4];
                    int4 apf = ap;  apf.x ^= S;  apf.z ^= S;      // flip odd kappa
                    int4 aqf = aq;  aqf.x ^= S;  aqf.z ^= S;
                    int4 aqn = aq;  aqn.x ^= S;  aqn.y ^= S;  aqn.z ^= S;  aqn.w ^= S;
                    int4 aqnf = aq; aqnf.y ^= S; aqnf.w ^= S;     // negate(flip)
                    bf16x8 AP   = *(bf16x8*)&ap;
                    bf16x8 APF  = *(bf16x8*)&apf;
                    bf16x8 AQ   = *(bf16x8*)&aq;
                    bf16x8 AQF  = *(bf16x8*)&aqf;
                    bf16x8 AQN  = *(bf16x8*)&aqn;
                    bf16x8 AQNF = *(bf16x8*)&aqnf;
                    accE[mt]  = __builtin_amdgcn_mfma_f32_16x16x32_bf16(AP,   BE, accE[mt],  0, 0, 0);
                    accE[mt]  = __builtin_amdgcn_mfma_f32_16x16x32_bf16(AQ,   BE, accE[mt],  0, 0, 0);
                    accO[mt]  = __builtin_amdgcn_mfma_f32_16x16x32_bf16(AP,   BO, accO[mt],  0, 0, 0);
                    accO[mt]  = __builtin_amdgcn_mfma_f32_16x16x32_bf16(AQN,  BO, accO[mt],  0, 0, 0);
                    accER[mt] = __builtin_amdgcn_mfma_f32_16x16x32_bf16(APF,  BE, accER[mt], 0, 0, 0);
                    accER[mt] = __builtin_amdgcn_mfma_f32_16x16x32_bf16(AQF,  BE, accER[mt], 0, 0, 0);
                    accOR[mt] = __builtin_amdgcn_mfma_f32_16x16x32_bf16(APF,  BO, accOR[mt], 0, 0, 0);
                    accOR[mt] = __builtin_amdgcn_mfma_f32_16x16x32_bf16(AQNF, BO, accOR[mt], 0, 0, 0);
                }
            }
        }
        __syncthreads();   // abt reads done; xbf may overwrite

        // ---- phase 3: two 32-frame halves: acc -> xbf -> parallel OLA ----
        #pragma unroll
        for (int h = 0; h < 2; ++h) {
            #pragma unroll
            for (int mt2 = 0; mt2 < 2; ++mt2) {
                int mtg = 2*h + mt2;
                int colE = wv*32 + 2*m0;
                #pragma unroll
                for (int r = 0; r < 4; ++r) {
                    int f_loc = mt2*16 + ac*4 + r;
                    float2 vL = make_float2(accE[mtg][r],  accO[mtg][r]);
                    float2 vR = make_float2(accER[mtg][r], accOR[mtg][r]);
                    *(float2*)&xbf[f_loc*516 + colE      ] = vL;
                    *(float2*)&xbf[f_loc*516 + colE + 256] = vR;
                }
            }
            __syncthreads();
            {
                // all 512 threads: column wE, 16 frames starting at fbE
                const int hfb = h*32 + fbE;
                float* orow = out + (size_t)row*32768
                                  + (size_t)(F0 + h*32 + fbE)*256 + wE;
                float sprev = (fbE == 0) ? 0.f
                              : (a0s[hfb - 1] + sgn * a256s[hfb - 1]);
                #pragma unroll
                for (int f = 0; f < 16; ++f) {
                    int fl = fbE + f;
                    int hf = hfb + f;
                    float s  = a0s[hf] + sgn * a256s[hf];
                    float x1 = xbf[fl*516 + wE] + s;
                    float x2p = (fbE == 0 && f == 0)
                                ? carry[wE]
                                : (xbf[(fl - 1)*516 + wE + 256] + sprev);
                    float v = fmaf(x1, h1, h2 * x2p);
                    __builtin_nontemporal_store(v, &orow[f*256]);
                    sprev = s;
                }
                if (tid < 256) {   // save frame-31 R-half (+s) for next half
                    float s31 = a0s[h*32 + 31] + sgn * a256s[h*32 + 31];
                    carry[wE] = xbf[31*516 + wE + 256] + s31;
                }
            }
            __syncthreads();   // xbf/carry settled before next fill / scan
        }
    }
}

// ------------------------------------------------------------------

extern "C" void kernel_launch(void* const* d_in, const int* in_sizes, int n_in,
                              void* d_out, int out_size, void* d_ws, size_t ws_size,
                              hipStream_t stream)
{
    const float* latents  = (const float*)d_in[0];
    const float* phase0_u = (const float*)d_in[1];
    const float* noise_u  = (const float*)d_in[2];
    const float* Win      = (const float*)d_in[3];
    const float* b_in     = (const float*)d_in[4];
    const float* Wh       = (const float*)d_in[5];
    const float* b_h      = (const float*)d_in[6];
    const float* Wout     = (const float*)d_in[7];
    const float* b_out    = (const float*)d_in[8];

    unsigned char* ws = (unsigned char*)d_ws;
    float*          out3  = (float*)(ws + OUT3_OFF);
    unsigned short* tpack = (unsigned short*)(ws + TPACK_OFF);
    float*          out   = (float*)d_out;

    dim3 gA(128, 3);
    mlp_kernel<<<gA, 512, 0, stream>>>(latents, Win, b_in, Wh, b_h, Wout, b_out, out3);
    tpack_init<<<32, 256, 0, stream>>>(tpack);
    synth_row<<<1024, 512, 0, stream>>>(out3, phase0_u, noise_u, tpack, out);
}

// Round 16
// 182.652 us; speedup vs baseline: 3.2815x; 1.2950x over previous
//
#include <hip/hip_runtime.h>
#include <hip/hip_bf16.h>

#define PI_F 3.14159265358979323846f

typedef short  bf16x8 __attribute__((ext_vector_type(8)));
typedef unsigned short u16x8 __attribute__((ext_vector_type(8)));
typedef float  f32x4  __attribute__((ext_vector_type(4)));

// ---- ws layout (bytes) ----
#define OUT3_OFF  0                       // [3][1024][257] f32 = 3,158,016 B
#define TPACK_OFF 3158016                 // [64 tiles][64][8] bf16 = 65,536 B

static __device__ __forceinline__ unsigned short f2bf(float x) {
    unsigned int u = __float_as_uint(x);
    unsigned int r = (u + 0x7fffu + ((u >> 16) & 1u)) >> 16;   // RNE
    return (unsigned short)r;
}

static __device__ __forceinline__ float sigm(float x) {
    return 1.f / (1.f + expf(-x));
}

static __device__ __forceinline__ float bf_lo(unsigned int u) {
    return __uint_as_float(u << 16);
}
static __device__ __forceinline__ float bf_hi(unsigned int u) {
    return __uint_as_float(u & 0xffff0000u);
}

// ------------------------------------------------------------------
// Kernel A: three LinearOutputStacks. 8 rows/block, 512 threads,
// row-half split (rows 0-3 / 4-7). grid (128,3) = 384 blocks.
// ------------------------------------------------------------------

__device__ __forceinline__ void ln512(float (*buf)[256], float* mrow, float* rrow)
{
    const int tid = threadIdx.x;
    const int lane = tid & 63, wv = tid >> 6;      // wave wv reduces row wv
    float s = 0.f, s2 = 0.f;
    #pragma unroll
    for (int j = 0; j < 4; j++) {
        float v = buf[wv][lane + 64*j];
        s += v; s2 += v*v;
    }
    #pragma unroll
    for (int o = 32; o > 0; o >>= 1) {
        s  += __shfl_xor(s,  o, 64);
        s2 += __shfl_xor(s2, o, 64);
    }
    if (lane == 0) {
        float m   = s * (1.f/256.f);
        float var = s2 * (1.f/256.f) - m*m;
        mrow[wv] = m;
        rrow[wv] = rsqrtf(var + 1e-5f);
    }
    __syncthreads();
    #pragma unroll
    for (int idx = tid; idx < 2048; idx += 512) {
        int r = idx >> 8, cc = idx & 255;
        buf[r][cc] = (buf[r][cc] - mrow[r]) * rrow[r];
    }
    __syncthreads();
}

// KDIM -> 256 matmul + bias + leaky_relu(0.2), row-half split
template<int KDIM>
__device__ __forceinline__ void mmvh(const float (*in)[KDIM],
                                     const float* __restrict__ W,
                                     const float* __restrict__ bias,
                                     float (*outb)[256])
{
    const int tid = threadIdx.x;
    const int c  = tid & 255;
    const int r0 = (tid >> 8) * 4;
    float acc[4] = {0.f, 0.f, 0.f, 0.f};
    const float* Wp = W + c;
    for (int l16 = 0; l16 < KDIM; l16 += 16) {
        float wbuf[16];
        #pragma unroll
        for (int j = 0; j < 16; j++) wbuf[j] = Wp[(size_t)(l16 + j)*256];
        #pragma unroll
        for (int q = 0; q < 4; q++) {
            f32x4 iq[4];
            #pragma unroll
            for (int r = 0; r < 4; r++) iq[r] = *(const f32x4*)&in[r0 + r][l16 + q*4];
            #pragma unroll
            for (int jj = 0; jj < 4; jj++)
                #pragma unroll
                for (int r = 0; r < 4; r++)
                    acc[r] = fmaf(iq[r][jj], wbuf[q*4 + jj], acc[r]);
        }
    }
    const float bb = bias[c];
    #pragma unroll
    for (int r = 0; r < 4; r++) {
        float v = acc[r] + bb;
        outb[r0 + r][c] = (v >= 0.f) ? v : 0.2f*v;
    }
}

__global__ __launch_bounds__(512) void mlp_kernel(
    const float* __restrict__ latents,
    const float* __restrict__ Win,  const float* __restrict__ b_in,
    const float* __restrict__ Wh,   const float* __restrict__ b_h,
    const float* __restrict__ Wout, const float* __restrict__ b_out,
    float* __restrict__ out3)
{
    __shared__ float bufA[8][128];
    __shared__ float bufB[8][256];
    __shared__ float bufC[8][256];
    __shared__ float mrow[8], rrow[8];

    const int tid  = threadIdx.x;
    const int s    = blockIdx.y;
    const int row0 = blockIdx.x * 8;
    const int c    = tid & 255;
    const int r0   = (tid >> 8) * 4;

    for (int idx = tid; idx < 8*128; idx += 512) {
        int r = idx >> 7, l = idx & 127;
        bufA[r][l] = latents[(size_t)(row0 + r)*128 + l];
    }
    __syncthreads();

    mmvh<128>(bufA, Win + (size_t)s*128*256, b_in + s*256, bufB);
    __syncthreads();
    ln512(bufB, mrow, rrow);

    mmvh<256>(bufB, Wh + ((size_t)s*2 + 0)*256*256, b_h + (s*2 + 0)*256, bufC);
    __syncthreads();
    ln512(bufC, mrow, rrow);

    mmvh<256>(bufC, Wh + ((size_t)s*2 + 1)*256*256, b_h + (s*2 + 1)*256, bufB);
    __syncthreads();
    ln512(bufB, mrow, rrow);

    // output layer: 256 -> 257 (+bias), raw
    {
        float acc[4] = {0.f, 0.f, 0.f, 0.f};
        const float* Wp = Wout + (size_t)s*256*257 + c;
        for (int l16 = 0; l16 < 256; l16 += 16) {
            float wbuf[16];
            #pragma unroll
            for (int j = 0; j < 16; j++) wbuf[j] = Wp[(size_t)(l16 + j)*257];
            #pragma unroll
            for (int q = 0; q < 4; q++) {
                f32x4 iq[4];
                #pragma unroll
                for (int r = 0; r < 4; r++) iq[r] = *(const f32x4*)&bufB[r0 + r][l16 + q*4];
                #pragma unroll
                for (int jj = 0; jj < 4; jj++)
                    #pragma unroll
                    for (int r = 0; r < 4; r++)
                        acc[r] = fmaf(iq[r][jj], wbuf[q*4 + jj], acc[r]);
            }
        }
        float bb = b_out[s*257 + c];
        #pragma unroll
        for (int r = 0; r < 4; r++)
            out3[((size_t)s*1024 + row0 + r0 + r)*257 + c] = acc[r] + bb;

        // column 256 (one thread per row)
        if (tid < 8) {
            const int r = tid;
            float a = 0.f;
            const float* Wp2 = Wout + (size_t)s*256*257 + 256;
            for (int l = 0; l < 256; ++l)
                a = fmaf(bufB[r][l], Wp2[(size_t)l*257], a);
            out3[((size_t)s*1024 + row0 + r)*257 + 256] = a + b_out[s*257 + 256];
        }
    }
}

// ------------------------------------------------------------------
// K1: pack the quarter iDFT basis (k-mirror + w-mirror + parity split).
// Source cols w = 0..127 only; kappa = k2/2+1 in [1,128].
// tile = ks*8 + wv;  wv -> wg = wv>>1 (32-col group), p = wv&1 (parity).
// lane l elem j: k2 = ks*32 + (l>>4)*8 + j; w = wg*32 + 2*(l&15) + p.
// 64 tiles x 1 KB = 64 KB.
// ------------------------------------------------------------------
__global__ __launch_bounds__(256) void tpack_init(unsigned short* __restrict__ tp)
{
    int g = blockIdx.x * 256 + threadIdx.x;      // 64*64 = 4096 threads exactly
    int tile = g >> 6, l = g & 63;
    int ks = tile >> 3;                          // 0..7
    int wv = tile & 7;
    int wg = wv >> 1, p = wv & 1;
    u16x8 v;
    #pragma unroll
    for (int j = 0; j < 8; ++j) {
        int k2 = ks*32 + ((l >> 4) << 3) + j;    // < 256
        int kap = (k2 >> 1) + 1;                 // 1..128
        int w  = wg*32 + 2*(l & 15) + p;         // < 128
        int m  = (kap * w) & 511;                // exact angle reduction
        float ang = (float)m * (PI_F / 256.f);
        float sn, cn; sincosf(ang, &sn, &cn);
        v[j] = f2bf((k2 & 1) ? sn : cn);
    }
    *(u16x8*)(tp + (size_t)g * 8) = v;
}

// ------------------------------------------------------------------
// K2: full-row fused scan + quarter-basis MFMA iDFT + Hann/OLA.
// grid 1024, block 512 (8 waves), __launch_bounds__(512,4): 2 blocks/CU.
// Base = round-13 (best verified).  NEW: w-mirror — each wave's single
// B tile (source cols w in [0,128), parity-split) produces FOUR outputs
// {x[w], x[w+256], x[256-w], x[512-w]} via sign-mask variants of the
// same A fragments (c_k(256-w)=(-1)^k c, s->-(-1)^k s; c(512-w)=c,
// s->-s; all (-1)^W parity factors equal (-1)^w).  tpack 128->64 KB.
// Cols x[128]/x[384] (not covered by the mirror) are computed from the
// stored bf16 coefficients with c/s(pi*k/2) in {0,+-1} before xbf
// overwrites abt.  x[0]'s col-512 image is predicated off; its col-256
// duplicate write is bit-identical (benign).
// ------------------------------------------------------------------
__global__ __launch_bounds__(512, 4) void synth_row(
    const float* __restrict__ out3,
    const float* __restrict__ phase0_u,
    const float* __restrict__ noise_u,
    const unsigned short* __restrict__ tpack,
    float* __restrict__ out)
{
    __shared__ __align__(16) unsigned int lds_u[16896];   // 67,584 B union
    __shared__ float a0s[64];
    __shared__ float a256s[64];
    __shared__ float pbuf[8][260];                        // 8,320 B
    __shared__ float xs128[64];
    __shared__ float xs384[64];

    unsigned int* abtP = lds_u;                  // [64][132] u32
    unsigned int* abtQ = lds_u + 64*132;         // [64][132] u32
    float*        xbf  = (float*)lds_u;          // [32][516] f32

    const int tid = threadIdx.x;
    const int row = blockIdx.x;
    const int b   = row >> 9;
    const int e   = row & 511;

    const float inv = 0.04419417382415922f;      // 1/sqrt(512)

    // ---- producer init (tid <= 256): phase recurrence only ----
    float pr = 0.f, dith_ = 0.f, gdd = 0.f;
    if (tid <= 256) {
        float dpre = out3[((size_t)2*1024 + row)*257 + tid];
        dith_ = sigm(dpre);
        float gd = (float)tid * (1.f/512.f);
        gdd = gd - 0.5f*dith_;                   // pr += fma(dith, nz, gdd)
        pr  = phase0_u[(size_t)row*257 + tid] - 0.5f;
    }
    // thread 256: Nyquist-bin evaluation state
    float m2 = 0.f, res2_ = 0.f;
    if (tid == 256) {
        float i2 = out3[((size_t)0*1024 + row)*257 + 256];
        float r2 = out3[((size_t)1*1024 + row)*257 + 256];
        res2_ = 0.5f + 0.4995f * sigm(r2);
        m2    = inv * i2;
    }

    // ---- consumer init (all threads): bin kc, frames j0..j0+3 ----
    const int kc = tid & 255;
    const int j0 = (tid >> 8) * 4;               // 0 or 4
    float m_base, rp1, rp2, rp3, res8;
    float bsgn = -1.f;
    unsigned int* tgt = abtP;                    // kc==0 never writes tgt
    {
        float ini  = out3[((size_t)0*1024 + row)*257 + kc];
        float rpre = out3[((size_t)1*1024 + row)*257 + kc];
        float res  = 0.5f + 0.4995f * sigm(rpre);
        float cs   = (kc == 0 ? 1.f : 2.f) * inv;
        rp1 = res;
        rp2 = res * res;
        rp3 = rp2 * res;
        float res4 = rp2 * rp2;
        res8 = res4 * res4;
        m_base = cs * ini;
        if (j0 == 4) m_base *= res4;
        if (kc >= 129)     { tgt = abtQ + (255 - kc); bsgn = 1.f; }
        else if (kc >= 1)  { tgt = abtP + (kc - 1); }
    }

    const float* nrow = noise_u + ((size_t)b*128*512 + e)*257;
    const size_t nstride = (size_t)512*257;

    // OLA constants for col w = tid (threads < 256)
    float h1 = 0.f, h2 = 0.f;
    {
        float c0 = __builtin_amdgcn_cosf((float)tid * (1.f/512.f));
        h1 = 0.5f - 0.5f*c0;                     // hann[tid]
        h2 = 0.5f + 0.5f*c0;                     // hann[tid+256]
    }
    const float sgn = (tid & 1) ? -1.f : 1.f;    // (-1)^w
    float tail = 0.f;

    const int l  = tid & 63;
    const int wv = tid >> 6;                     // 0..7: one 16-src-col tile
    const int m0 = l & 15;
    const int ac = l >> 4;
    const int wsrc = (wv >> 1)*32 + 2*m0 + (wv & 1);   // source col 0..127
    const int c1 = wsrc;                         // x[w]
    const int c2 = wsrc + 256;                   // x[w+256]
    const int c3 = 256 - wsrc;                   // x[256-w]
    const int c4 = 512 - wsrc;                   // x[512-w] (invalid at w=0)
    const bool c4ok = (wsrc != 0);
    const int4* abtP4 = (const int4*)abtP;       // row stride 33 int4
    const int4* abtQ4 = (const int4*)abtQ;
    const int4* Tp    = (const int4*)tpack;
    const unsigned int S   = 0x80008000u;
    const unsigned int B31 = 0x80000000u;
    const unsigned int mq  = (wv & 1) ? S : 0u;  // parity (-1)^w on Q

    for (int sweep = 0; sweep < 2; ++sweep) {
        const int F0 = sweep * 64;

        // ---- phase 1: producer/consumer scan, 8 groups of 8 frames ----
        for (int g = 0; g < 8; ++g) {
            if (tid <= 256) {
                float nzb[8];
                #pragma unroll
                for (int j = 0; j < 8; ++j) {
                    int t = F0 + g*8 + j;
                    nzb[j] = (t >= 1) ? __builtin_nontemporal_load(
                                            &nrow[(size_t)t*nstride + tid]) : 0.5f;
                }
                #pragma unroll
                for (int j = 0; j < 8; ++j) {
                    int t = F0 + g*8 + j;
                    if (t >= 1) pr += fmaf(dith_, nzb[j], gdd);
                    pbuf[j][tid] = pr;
                    if (tid == 256) {            // Nyquist: cos only
                        if (t >= 1) m2 *= res2_;
                        float fr = pr - floorf(pr);
                        a256s[g*8 + j] = m2 * __builtin_amdgcn_cosf(fr);
                    }
                }
            } else if (g == 0 && tid >= 448) {
                // zero abtQ kappa=128 column (clobbered by xbf each sweep)
                abtQ[(tid - 448)*132 + 127] = 0;
            }
            __syncthreads();

            // consumers: all 512 threads, 4 (bin,frame) items each
            {
                const int fb = g*8 + j0;
                float mv[4];
                mv[0] = m_base;
                mv[1] = m_base * rp1;
                mv[2] = m_base * rp2;
                mv[3] = m_base * rp3;
                #pragma unroll
                for (int q = 0; q < 4; ++q) {
                    float p  = pbuf[j0 + q][kc];
                    float fr = p - floorf(p);
                    float sn = __builtin_amdgcn_sinf(fr);
                    float cn = __builtin_amdgcn_cosf(fr);
                    float a  = mv[q] * cn;
                    if (kc == 0) {
                        a0s[fb + q] = a;
                    } else {
                        float bv = bsgn * mv[q] * sn;
                        tgt[(fb + q)*132] =
                            (unsigned int)f2bf(a) | ((unsigned int)f2bf(bv) << 16);
                    }
                }
                m_base *= res8;
            }
            __syncthreads();
        }

        // ---- phase 2: MFMA  M=64, N=128 src cols x 4 mirror variants ----
        f32x4 acc1[4], acc2[4], acc3[4], acc4[4];
        #pragma unroll
        for (int mt = 0; mt < 4; ++mt) {
            acc1[mt] = (f32x4){0.f, 0.f, 0.f, 0.f};
            acc2[mt] = (f32x4){0.f, 0.f, 0.f, 0.f};
            acc3[mt] = (f32x4){0.f, 0.f, 0.f, 0.f};
            acc4[mt] = (f32x4){0.f, 0.f, 0.f, 0.f};
        }
        {
            const int r0g = m0*33 + ac;
            for (int ks = 0; ks < 8; ++ks) {
                int4 bi = Tp[(size_t)((ks*8 + wv) << 6) + l];
                bf16x8 B = *(bf16x8*)&bi;
                #pragma unroll
                for (int mt = 0; mt < 4; ++mt) {
                    // P coefficients, 4 mirror variants via XOR chain
                    int4 t = abtP4[r0g + mt*528 + ks*4];
                    acc1[mt] = __builtin_amdgcn_mfma_f32_16x16x32_bf16(*(bf16x8*)&t, B, acc1[mt], 0, 0, 0);
                    t.x ^= S;   t.z ^= S;                              // v2: flip odd kappa
                    acc2[mt] = __builtin_amdgcn_mfma_f32_16x16x32_bf16(*(bf16x8*)&t, B, acc2[mt], 0, 0, 0);
                    t.x ^= B31; t.y ^= B31; t.z ^= B31; t.w ^= B31;    // v3
                    acc3[mt] = __builtin_amdgcn_mfma_f32_16x16x32_bf16(*(bf16x8*)&t, B, acc3[mt], 0, 0, 0);
                    t.x ^= S;   t.z ^= S;                              // v4: b negated
                    acc4[mt] = __builtin_amdgcn_mfma_f32_16x16x32_bf16(*(bf16x8*)&t, B, acc4[mt], 0, 0, 0);
                    // Q coefficients (parity factor mq), same chain
                    int4 u = abtQ4[r0g + mt*528 + ks*4];
                    u.x ^= mq;  u.y ^= mq;  u.z ^= mq;  u.w ^= mq;
                    acc1[mt] = __builtin_amdgcn_mfma_f32_16x16x32_bf16(*(bf16x8*)&u, B, acc1[mt], 0, 0, 0);
                    u.x ^= S;   u.z ^= S;
                    acc2[mt] = __builtin_amdgcn_mfma_f32_16x16x32_bf16(*(bf16x8*)&u, B, acc2[mt], 0, 0, 0);
                    u.x ^= B31; u.y ^= B31; u.z ^= B31; u.w ^= B31;
                    acc3[mt] = __builtin_amdgcn_mfma_f32_16x16x32_bf16(*(bf16x8*)&u, B, acc3[mt], 0, 0, 0);
                    u.x ^= S;   u.z ^= S;
                    acc4[mt] = __builtin_amdgcn_mfma_f32_16x16x32_bf16(*(bf16x8*)&u, B, acc4[mt], 0, 0, 0);
                }
            }
        }

        // ---- phase 2.5: specials x[128], x[384] from stored bf16 coeffs ----
        // c(pi*kap/2), s(pi*kap/2) in {0,+-1}; x384 = x128 with odd-kappa
        // b-terms negated.  8 lanes per frame, shfl-reduce.
        {
            const int f8 = tid >> 3;             // frame 0..63
            const int i8 = tid & 7;              // kappa chunk
            float s128 = 0.f, s384 = 0.f;
            #pragma unroll
            for (int q = 0; q < 16; ++q) {
                int ki = i8*16 + q;              // kappa = ki+1
                unsigned int up = abtP[f8*132 + ki];
                unsigned int uq = abtQ[f8*132 + ki];
                if ((q + 1) & 1) {               // kappa odd: sin terms
                    float sg = ((q + 1) & 2) ? -1.f : 1.f;
                    float bsum = bf_hi(up) + bf_hi(uq);
                    s128 += sg * bsum;
                    s384 -= sg * bsum;
                } else {                         // kappa even: cos terms
                    float sg = ((q + 1) & 2) ? -1.f : 1.f;
                    float asum = bf_lo(up) + bf_lo(uq);
                    s128 += sg * asum;
                    s384 += sg * asum;
                }
            }
            #pragma unroll
            for (int o = 1; o < 8; o <<= 1) {
                s128 += __shfl_xor(s128, o, 64);
                s384 += __shfl_xor(s384, o, 64);
            }
            if (i8 == 0) { xs128[f8] = s128; xs384[f8] = s384; }
        }
        __syncthreads();   // abt reads done; xbf may overwrite

        // ---- phase 3: two 32-frame halves: acc -> xbf -> Hann+OLA ----
        #pragma unroll
        for (int h = 0; h < 2; ++h) {
            #pragma unroll
            for (int mt2 = 0; mt2 < 2; ++mt2) {
                int mtg = 2*h + mt2;
                #pragma unroll
                for (int r = 0; r < 4; ++r) {
                    int f_loc = mt2*16 + ac*4 + r;
                    float* xr = &xbf[f_loc*516];
                    xr[c1] = acc1[mtg][r];
                    xr[c2] = acc2[mtg][r];
                    xr[c3] = acc3[mtg][r];
                    if (c4ok) xr[c4] = acc4[mtg][r];
                }
            }
            if (tid < 32) {
                xbf[tid*516 + 128] = xs128[h*32 + tid];
                xbf[tid*516 + 384] = xs384[h*32 + tid];
            }
            __syncthreads();
            if (tid < 256) {
                float* orow = out + (size_t)row*32768 + (size_t)(F0 + h*32)*256 + tid;
                #pragma unroll
                for (int f = 0; f < 32; ++f) {
                    int hf = h*32 + f;
                    float s  = a0s[hf] + sgn * a256s[hf];
                    float x1 = xbf[f*516 + tid] + s;
                    float x2 = xbf[f*516 + tid + 256] + s;
                    float v  = fmaf(x1, h1, tail);
                    tail = x2 * h2;
                    __builtin_nontemporal_store(v, &orow[f*256]);
                }
            }
            __syncthreads();   // xbf reads done before next write / next abt
        }
    }
}

// ------------------------------------------------------------------

extern "C" void kernel_launch(void* const* d_in, const int* in_sizes, int n_in,
                              void* d_out, int out_size, void* d_ws, size_t ws_size,
                              hipStream_t stream)
{
    const float* latents  = (const float*)d_in[0];
    const float* phase0_u = (const float*)d_in[1];
    const float* noise_u  = (const float*)d_in[2];
    const float* Win      = (const float*)d_in[3];
    const float* b_in     = (const float*)d_in[4];
    const float* Wh       = (const float*)d_in[5];
    const float* b_h      = (const float*)d_in[6];
    const float* Wout     = (const float*)d_in[7];
    const float* b_out    = (const float*)d_in[8];

    unsigned char* ws = (unsigned char*)d_ws;
    float*          out3  = (float*)(ws + OUT3_OFF);
    unsigned short* tpack = (unsigned short*)(ws + TPACK_OFF);
    float*          out   = (float*)d_out;

    dim3 gA(128, 3);
    mlp_kernel<<<gA, 512, 0, stream>>>(latents, Win, b_in, Wh, b_h, Wout, b_out, out3);
    tpack_init<<<16, 256, 0, stream>>>(tpack);
    synth_row<<<1024, 512, 0, stream>>>(out3, phase0_u, noise_u, tpack, out);
}

// Round 17
// 175.811 us; speedup vs baseline: 3.4092x; 1.0389x over previous
//
#include <hip/hip_runtime.h>
#include <hip/hip_bf16.h>

#define PI_F 3.14159265358979323846f

typedef short  bf16x8 __attribute__((ext_vector_type(8)));
typedef unsigned short u16x8 __attribute__((ext_vector_type(8)));
typedef float  f32x4  __attribute__((ext_vector_type(4)));

// ---- ws layout (bytes) ----
#define OUT3_OFF  0                       // [3][1024][257] f32 = 3,158,016 B
#define TPACK_OFF 3158016                 // [64 tiles][64][8] bf16 = 65,536 B

static __device__ __forceinline__ unsigned short f2bf(float x) {
    unsigned int u = __float_as_uint(x);
    unsigned int r = (u + 0x7fffu + ((u >> 16) & 1u)) >> 16;   // RNE
    return (unsigned short)r;
}

static __device__ __forceinline__ float sigm(float x) {
    return 1.f / (1.f + expf(-x));
}

static __device__ __forceinline__ float bf_lo(unsigned int u) {
    return __uint_as_float(u << 16);
}
static __device__ __forceinline__ float bf_hi(unsigned int u) {
    return __uint_as_float(u & 0xffff0000u);
}

// ------------------------------------------------------------------
// Kernel A: three LinearOutputStacks. 8 rows/block, 512 threads,
// row-half split (rows 0-3 / 4-7). grid (128,3) = 384 blocks.
// ------------------------------------------------------------------

__device__ __forceinline__ void ln512(float (*buf)[256], float* mrow, float* rrow)
{
    const int tid = threadIdx.x;
    const int lane = tid & 63, wv = tid >> 6;      // wave wv reduces row wv
    float s = 0.f, s2 = 0.f;
    #pragma unroll
    for (int j = 0; j < 4; j++) {
        float v = buf[wv][lane + 64*j];
        s += v; s2 += v*v;
    }
    #pragma unroll
    for (int o = 32; o > 0; o >>= 1) {
        s  += __shfl_xor(s,  o, 64);
        s2 += __shfl_xor(s2, o, 64);
    }
    if (lane == 0) {
        float m   = s * (1.f/256.f);
        float var = s2 * (1.f/256.f) - m*m;
        mrow[wv] = m;
        rrow[wv] = rsqrtf(var + 1e-5f);
    }
    __syncthreads();
    #pragma unroll
    for (int idx = tid; idx < 2048; idx += 512) {
        int r = idx >> 8, cc = idx & 255;
        buf[r][cc] = (buf[r][cc] - mrow[r]) * rrow[r];
    }
    __syncthreads();
}

// KDIM -> 256 matmul + bias + leaky_relu(0.2), row-half split
template<int KDIM>
__device__ __forceinline__ void mmvh(const float (*in)[KDIM],
                                     const float* __restrict__ W,
                                     const float* __restrict__ bias,
                                     float (*outb)[256])
{
    const int tid = threadIdx.x;
    const int c  = tid & 255;
    const int r0 = (tid >> 8) * 4;
    float acc[4] = {0.f, 0.f, 0.f, 0.f};
    const float* Wp = W + c;
    for (int l16 = 0; l16 < KDIM; l16 += 16) {
        float wbuf[16];
        #pragma unroll
        for (int j = 0; j < 16; j++) wbuf[j] = Wp[(size_t)(l16 + j)*256];
        #pragma unroll
        for (int q = 0; q < 4; q++) {
            f32x4 iq[4];
            #pragma unroll
            for (int r = 0; r < 4; r++) iq[r] = *(const f32x4*)&in[r0 + r][l16 + q*4];
            #pragma unroll
            for (int jj = 0; jj < 4; jj++)
                #pragma unroll
                for (int r = 0; r < 4; r++)
                    acc[r] = fmaf(iq[r][jj], wbuf[q*4 + jj], acc[r]);
        }
    }
    const float bb = bias[c];
    #pragma unroll
    for (int r = 0; r < 4; r++) {
        float v = acc[r] + bb;
        outb[r0 + r][c] = (v >= 0.f) ? v : 0.2f*v;
    }
}

__global__ __launch_bounds__(512) void mlp_kernel(
    const float* __restrict__ latents,
    const float* __restrict__ Win,  const float* __restrict__ b_in,
    const float* __restrict__ Wh,   const float* __restrict__ b_h,
    const float* __restrict__ Wout, const float* __restrict__ b_out,
    float* __restrict__ out3)
{
    __shared__ float bufA[8][128];
    __shared__ float bufB[8][256];
    __shared__ float bufC[8][256];
    __shared__ float mrow[8], rrow[8];

    const int tid  = threadIdx.x;
    const int s    = blockIdx.y;
    const int row0 = blockIdx.x * 8;
    const int c    = tid & 255;
    const int r0   = (tid >> 8) * 4;

    for (int idx = tid; idx < 8*128; idx += 512) {
        int r = idx >> 7, l = idx & 127;
        bufA[r][l] = latents[(size_t)(row0 + r)*128 + l];
    }
    __syncthreads();

    mmvh<128>(bufA, Win + (size_t)s*128*256, b_in + s*256, bufB);
    __syncthreads();
    ln512(bufB, mrow, rrow);

    mmvh<256>(bufB, Wh + ((size_t)s*2 + 0)*256*256, b_h + (s*2 + 0)*256, bufC);
    __syncthreads();
    ln512(bufC, mrow, rrow);

    mmvh<256>(bufC, Wh + ((size_t)s*2 + 1)*256*256, b_h + (s*2 + 1)*256, bufB);
    __syncthreads();
    ln512(bufB, mrow, rrow);

    // output layer: 256 -> 257 (+bias), raw
    {
        float acc[4] = {0.f, 0.f, 0.f, 0.f};
        const float* Wp = Wout + (size_t)s*256*257 + c;
        for (int l16 = 0; l16 < 256; l16 += 16) {
            float wbuf[16];
            #pragma unroll
            for (int j = 0; j < 16; j++) wbuf[j] = Wp[(size_t)(l16 + j)*257];
            #pragma unroll
            for (int q = 0; q < 4; q++) {
                f32x4 iq[4];
                #pragma unroll
                for (int r = 0; r < 4; r++) iq[r] = *(const f32x4*)&bufB[r0 + r][l16 + q*4];
                #pragma unroll
                for (int jj = 0; jj < 4; jj++)
                    #pragma unroll
                    for (int r = 0; r < 4; r++)
                        acc[r] = fmaf(iq[r][jj], wbuf[q*4 + jj], acc[r]);
            }
        }
        float bb = b_out[s*257 + c];
        #pragma unroll
        for (int r = 0; r < 4; r++)
            out3[((size_t)s*1024 + row0 + r0 + r)*257 + c] = acc[r] + bb;

        // column 256 (one thread per row)
        if (tid < 8) {
            const int r = tid;
            float a = 0.f;
            const float* Wp2 = Wout + (size_t)s*256*257 + 256;
            for (int l = 0; l < 256; ++l)
                a = fmaf(bufB[r][l], Wp2[(size_t)l*257], a);
            out3[((size_t)s*1024 + row0 + r)*257 + 256] = a + b_out[s*257 + 256];
        }
    }
}

// ------------------------------------------------------------------
// K1: pack the quarter iDFT basis (k-mirror + w-mirror + parity split).
// Source cols w = 0..127 only; kappa = k2/2+1 in [1,128].
// tile = ks*8 + wv;  wv -> wg = wv>>1 (32-col group), p = wv&1 (parity).
// lane l elem j: k2 = ks*32 + (l>>4)*8 + j; w = wg*32 + 2*(l&15) + p.
// 64 tiles x 1 KB = 64 KB.
// ------------------------------------------------------------------
__global__ __launch_bounds__(256) void tpack_init(unsigned short* __restrict__ tp)
{
    int g = blockIdx.x * 256 + threadIdx.x;      // 64*64 = 4096 threads exactly
    int tile = g >> 6, l = g & 63;
    int ks = tile >> 3;                          // 0..7
    int wv = tile & 7;
    int wg = wv >> 1, p = wv & 1;
    u16x8 v;
    #pragma unroll
    for (int j = 0; j < 8; ++j) {
        int k2 = ks*32 + ((l >> 4) << 3) + j;    // < 256
        int kap = (k2 >> 1) + 1;                 // 1..128
        int w  = wg*32 + 2*(l & 15) + p;         // < 128
        int m  = (kap * w) & 511;                // exact angle reduction
        float ang = (float)m * (PI_F / 256.f);
        float sn, cn; sincosf(ang, &sn, &cn);
        v[j] = f2bf((k2 & 1) ? sn : cn);
    }
    *(u16x8*)(tp + (size_t)g * 8) = v;
}

// ------------------------------------------------------------------
// K2: full-row fused scan + quarter-basis MFMA iDFT + Hann/OLA.
// grid 1024, block 512 (8 waves), __launch_bounds__(512,4): 2 blocks/CU.
// Base = round-16.  NEW: P/Q COMBINE — since P (k=1..128) and Q
// (k=129..255, stored mirrored at kappa=256-k) multiply the SAME basis
// columns, an LDS pass forms R_even = P+Q, R_odd = P-Q (in place).
// Each wave (fixed column parity) then needs ONE A-fragment per
// (ks,mt): MFMA count HALVES (512->256/block), mq masks vanish,
// fragment loads halve.  kappa=128 (no Q partner) handled by the
// already-zeroed abtQ column.  Specials read combined E directly.
// ------------------------------------------------------------------
__global__ __launch_bounds__(512, 4) void synth_row(
    const float* __restrict__ out3,
    const float* __restrict__ phase0_u,
    const float* __restrict__ noise_u,
    const unsigned short* __restrict__ tpack,
    float* __restrict__ out)
{
    __shared__ __align__(16) unsigned int lds_u[16896];   // 67,584 B union
    __shared__ float a0s[64];
    __shared__ float a256s[64];
    __shared__ float pbuf[8][260];                        // 8,320 B
    __shared__ float xs128[64];
    __shared__ float xs384[64];

    unsigned int* abtP = lds_u;                  // [64][132] u32 (P -> R_even)
    unsigned int* abtQ = lds_u + 64*132;         // [64][132] u32 (Q -> R_odd)
    float*        xbf  = (float*)lds_u;          // [32][516] f32

    const int tid = threadIdx.x;
    const int row = blockIdx.x;
    const int b   = row >> 9;
    const int e   = row & 511;

    const float inv = 0.04419417382415922f;      // 1/sqrt(512)

    // ---- producer init (tid <= 256): phase recurrence only ----
    float pr = 0.f, dith_ = 0.f, gdd = 0.f;
    if (tid <= 256) {
        float dpre = out3[((size_t)2*1024 + row)*257 + tid];
        dith_ = sigm(dpre);
        float gd = (float)tid * (1.f/512.f);
        gdd = gd - 0.5f*dith_;                   // pr += fma(dith, nz, gdd)
        pr  = phase0_u[(size_t)row*257 + tid] - 0.5f;
    }
    // thread 256: Nyquist-bin evaluation state
    float m2 = 0.f, res2_ = 0.f;
    if (tid == 256) {
        float i2 = out3[((size_t)0*1024 + row)*257 + 256];
        float r2 = out3[((size_t)1*1024 + row)*257 + 256];
        res2_ = 0.5f + 0.4995f * sigm(r2);
        m2    = inv * i2;
    }

    // ---- consumer init (all threads): bin kc, frames j0..j0+3 ----
    const int kc = tid & 255;
    const int j0 = (tid >> 8) * 4;               // 0 or 4
    float m_base, rp1, rp2, rp3, res8;
    float bsgn = -1.f;
    unsigned int* tgt = abtP;                    // kc==0 never writes tgt
    {
        float ini  = out3[((size_t)0*1024 + row)*257 + kc];
        float rpre = out3[((size_t)1*1024 + row)*257 + kc];
        float res  = 0.5f + 0.4995f * sigm(rpre);
        float cs   = (kc == 0 ? 1.f : 2.f) * inv;
        rp1 = res;
        rp2 = res * res;
        rp3 = rp2 * res;
        float res4 = rp2 * rp2;
        res8 = res4 * res4;
        m_base = cs * ini;
        if (j0 == 4) m_base *= res4;
        if (kc >= 129)     { tgt = abtQ + (255 - kc); bsgn = 1.f; }
        else if (kc >= 1)  { tgt = abtP + (kc - 1); }
    }

    const float* nrow = noise_u + ((size_t)b*128*512 + e)*257;
    const size_t nstride = (size_t)512*257;

    // OLA constants for col w = tid (threads < 256)
    float h1 = 0.f, h2 = 0.f;
    {
        float c0 = __builtin_amdgcn_cosf((float)tid * (1.f/512.f));
        h1 = 0.5f - 0.5f*c0;                     // hann[tid]
        h2 = 0.5f + 0.5f*c0;                     // hann[tid+256]
    }
    const float sgn = (tid & 1) ? -1.f : 1.f;    // (-1)^w
    float tail = 0.f;

    const int l  = tid & 63;
    const int wv = tid >> 6;                     // 0..7: one 16-src-col tile
    const int m0 = l & 15;
    const int ac = l >> 4;
    const int wsrc = (wv >> 1)*32 + 2*m0 + (wv & 1);   // source col 0..127
    const int c1 = wsrc;                         // x[w]
    const int c2 = wsrc + 256;                   // x[w+256]
    const int c3 = 256 - wsrc;                   // x[256-w]
    const int c4 = 512 - wsrc;                   // x[512-w] (invalid at w=0)
    const bool c4ok = (wsrc != 0);
    const int4* abtP4 = (const int4*)abtP;       // row stride 33 int4
    const int4* abtQ4 = (const int4*)abtQ;
    const int4* abtR4 = (wv & 1) ? abtQ4 : abtP4;   // parity-selected R
    const int4* Tp    = (const int4*)tpack;
    const unsigned int S   = 0x80008000u;
    const unsigned int B31 = 0x80000000u;

    for (int sweep = 0; sweep < 2; ++sweep) {
        const int F0 = sweep * 64;

        // ---- phase 1: producer/consumer scan, 8 groups of 8 frames ----
        for (int g = 0; g < 8; ++g) {
            if (tid <= 256) {
                float nzb[8];
                #pragma unroll
                for (int j = 0; j < 8; ++j) {
                    int t = F0 + g*8 + j;
                    nzb[j] = (t >= 1) ? __builtin_nontemporal_load(
                                            &nrow[(size_t)t*nstride + tid]) : 0.5f;
                }
                #pragma unroll
                for (int j = 0; j < 8; ++j) {
                    int t = F0 + g*8 + j;
                    if (t >= 1) pr += fmaf(dith_, nzb[j], gdd);
                    pbuf[j][tid] = pr;
                    if (tid == 256) {            // Nyquist: cos only
                        if (t >= 1) m2 *= res2_;
                        float fr = pr - floorf(pr);
                        a256s[g*8 + j] = m2 * __builtin_amdgcn_cosf(fr);
                    }
                }
            } else if (g == 0 && tid >= 448) {
                // zero abtQ kappa=128 column (clobbered by xbf each sweep)
                abtQ[(tid - 448)*132 + 127] = 0;
            }
            __syncthreads();

            // consumers: all 512 threads, 4 (bin,frame) items each
            {
                const int fb = g*8 + j0;
                float mv[4];
                mv[0] = m_base;
                mv[1] = m_base * rp1;
                mv[2] = m_base * rp2;
                mv[3] = m_base * rp3;
                #pragma unroll
                for (int q = 0; q < 4; ++q) {
                    float p  = pbuf[j0 + q][kc];
                    float fr = p - floorf(p);
                    float sn = __builtin_amdgcn_sinf(fr);
                    float cn = __builtin_amdgcn_cosf(fr);
                    float a  = mv[q] * cn;
                    if (kc == 0) {
                        a0s[fb + q] = a;
                    } else {
                        float bv = bsgn * mv[q] * sn;
                        tgt[(fb + q)*132] =
                            (unsigned int)f2bf(a) | ((unsigned int)f2bf(bv) << 16);
                    }
                }
                m_base *= res8;
            }
            __syncthreads();
        }

        // ---- phase 1.5: P/Q combine (in place): P<-P+Q, Q<-P-Q ----
        {
            #pragma unroll
            for (int i = 0; i < 16; ++i) {
                int idx = tid + i*512;           // 0..8191
                int f  = idx >> 7, ki = idx & 127;
                int o  = f*132 + ki;
                unsigned int up = abtP[o];
                unsigned int uq = abtQ[o];
                float aP = bf_lo(up), bP = bf_hi(up);
                float aQ = bf_lo(uq), bQ = bf_hi(uq);
                abtP[o] = (unsigned int)f2bf(aP + aQ)
                        | ((unsigned int)f2bf(bP + bQ) << 16);
                abtQ[o] = (unsigned int)f2bf(aP - aQ)
                        | ((unsigned int)f2bf(bP - bQ) << 16);
            }
        }
        __syncthreads();

        // ---- phase 2: MFMA  M=64, N=128 src cols x 4 mirror variants ----
        // one fragment per (ks,mt) from the parity-matched combined table
        f32x4 acc1[4], acc2[4], acc3[4], acc4[4];
        #pragma unroll
        for (int mt = 0; mt < 4; ++mt) {
            acc1[mt] = (f32x4){0.f, 0.f, 0.f, 0.f};
            acc2[mt] = (f32x4){0.f, 0.f, 0.f, 0.f};
            acc3[mt] = (f32x4){0.f, 0.f, 0.f, 0.f};
            acc4[mt] = (f32x4){0.f, 0.f, 0.f, 0.f};
        }
        {
            const int r0g = m0*33 + ac;
            for (int ks = 0; ks < 8; ++ks) {
                int4 bi = Tp[(size_t)((ks*8 + wv) << 6) + l];
                bf16x8 B = *(bf16x8*)&bi;
                #pragma unroll
                for (int mt = 0; mt < 4; ++mt) {
                    int4 t = abtR4[r0g + mt*528 + ks*4];
                    acc1[mt] = __builtin_amdgcn_mfma_f32_16x16x32_bf16(*(bf16x8*)&t, B, acc1[mt], 0, 0, 0);
                    t.x ^= S;   t.z ^= S;                              // v2: flip odd kappa
                    acc2[mt] = __builtin_amdgcn_mfma_f32_16x16x32_bf16(*(bf16x8*)&t, B, acc2[mt], 0, 0, 0);
                    t.x ^= B31; t.y ^= B31; t.z ^= B31; t.w ^= B31;    // v3
                    acc3[mt] = __builtin_amdgcn_mfma_f32_16x16x32_bf16(*(bf16x8*)&t, B, acc3[mt], 0, 0, 0);
                    t.x ^= S;   t.z ^= S;                              // v4: b negated
                    acc4[mt] = __builtin_amdgcn_mfma_f32_16x16x32_bf16(*(bf16x8*)&t, B, acc4[mt], 0, 0, 0);
                }
            }
        }

        // ---- phase 2.5: specials x[128], x[384] from combined E coeffs ----
        // c(pi*kap/2), s(pi*kap/2) in {0,+-1}; x384 = x128 with b negated.
        {
            const int f8 = tid >> 3;             // frame 0..63
            const int i8 = tid & 7;              // kappa chunk
            float s128 = 0.f, s384 = 0.f;
            #pragma unroll
            for (int q = 0; q < 16; ++q) {
                int ki = i8*16 + q;              // kappa = ki+1
                unsigned int ue = abtP[f8*132 + ki];
                if ((q + 1) & 1) {               // kappa odd: sin terms
                    float sg = ((q + 1) & 2) ? -1.f : 1.f;
                    float bsum = bf_hi(ue);
                    s128 += sg * bsum;
                    s384 -= sg * bsum;
                } else {                         // kappa even: cos terms
                    float sg = ((q + 1) & 2) ? -1.f : 1.f;
                    float asum = bf_lo(ue);
                    s128 += sg * asum;
                    s384 += sg * asum;
                }
            }
            #pragma unroll
            for (int o = 1; o < 8; o <<= 1) {
                s128 += __shfl_xor(s128, o, 64);
                s384 += __shfl_xor(s384, o, 64);
            }
            if (i8 == 0) { xs128[f8] = s128; xs384[f8] = s384; }
        }
        __syncthreads();   // abt reads done; xbf may overwrite

        // ---- phase 3: two 32-frame halves: acc -> xbf -> Hann+OLA ----
        #pragma unroll
        for (int h = 0; h < 2; ++h) {
            #pragma unroll
            for (int mt2 = 0; mt2 < 2; ++mt2) {
                int mtg = 2*h + mt2;
                #pragma unroll
                for (int r = 0; r < 4; ++r) {
                    int f_loc = mt2*16 + ac*4 + r;
                    float* xr = &xbf[f_loc*516];
                    xr[c1] = acc1[mtg][r];
                    xr[c2] = acc2[mtg][r];
                    xr[c3] = acc3[mtg][r];
                    if (c4ok) xr[c4] = acc4[mtg][r];
                }
            }
            if (tid < 32) {
                xbf[tid*516 + 128] = xs128[h*32 + tid];
                xbf[tid*516 + 384] = xs384[h*32 + tid];
            }
            __syncthreads();
            if (tid < 256) {
                float* orow = out + (size_t)row*32768 + (size_t)(F0 + h*32)*256 + tid;
                #pragma unroll
                for (int f = 0; f < 32; ++f) {
                    int hf = h*32 + f;
                    float s  = a0s[hf] + sgn * a256s[hf];
                    float x1 = xbf[f*516 + tid] + s;
                    float x2 = xbf[f*516 + tid + 256] + s;
                    float v  = fmaf(x1, h1, tail);
                    tail = x2 * h2;
                    __builtin_nontemporal_store(v, &orow[f*256]);
                }
            }
            __syncthreads();   // xbf reads done before next write / next abt
        }
    }
}

// ------------------------------------------------------------------

extern "C" void kernel_launch(void* const* d_in, const int* in_sizes, int n_in,
                              void* d_out, int out_size, void* d_ws, size_t ws_size,
                              hipStream_t stream)
{
    const float* latents  = (const float*)d_in[0];
    const float* phase0_u = (const float*)d_in[1];
    const float* noise_u  = (const float*)d_in[2];
    const float* Win      = (const float*)d_in[3];
    const float* b_in     = (const float*)d_in[4];
    const float* Wh       = (const float*)d_in[5];
    const float* b_h      = (const float*)d_in[6];
    const float* Wout     = (const float*)d_in[7];
    const float* b_out    = (const float*)d_in[8];

    unsigned char* ws = (unsigned char*)d_ws;
    float*          out3  = (float*)(ws + OUT3_OFF);
    unsigned short* tpack = (unsigned short*)(ws + TPACK_OFF);
    float*          out   = (float*)d_out;

    dim3 gA(128, 3);
    mlp_kernel<<<gA, 512, 0, stream>>>(latents, Win, b_in, Wh, b_h, Wout, b_out, out3);
    tpack_init<<<16, 256, 0, stream>>>(tpack);
    synth_row<<<1024, 512, 0, stream>>>(out3, phase0_u, noise_u, tpack, out);
}

// Round 18
// 168.793 us; speedup vs baseline: 3.5509x; 1.0416x over previous
//
#include <hip/hip_runtime.h>
#include <hip/hip_bf16.h>

#define PI_F 3.14159265358979323846f

typedef short  bf16x8 __attribute__((ext_vector_type(8)));
typedef unsigned short u16x8 __attribute__((ext_vector_type(8)));
typedef float  f32x4  __attribute__((ext_vector_type(4)));

// ---- ws layout (bytes) ----
#define OUT3_OFF  0                       // [3][1024][257] f32 = 3,158,016 B
#define TPACK_OFF 3158016                 // [64 tiles][64][8] bf16 = 65,536 B

static __device__ __forceinline__ unsigned short f2bf(float x) {
    unsigned int u = __float_as_uint(x);
    unsigned int r = (u + 0x7fffu + ((u >> 16) & 1u)) >> 16;   // RNE
    return (unsigned short)r;
}

// pack two f32 -> one u32 of 2 bf16 (lo = a, hi = b) in ONE instruction
static __device__ __forceinline__ unsigned int pk_bf16(float a, float b) {
    unsigned int r;
    asm("v_cvt_pk_bf16_f32 %0, %1, %2" : "=v"(r) : "v"(a), "v"(b));
    return r;
}

static __device__ __forceinline__ float sigm(float x) {
    return 1.f / (1.f + expf(-x));
}

static __device__ __forceinline__ float bf_lo(unsigned int u) {
    return __uint_as_float(u << 16);
}
static __device__ __forceinline__ float bf_hi(unsigned int u) {
    return __uint_as_float(u & 0xffff0000u);
}

// ------------------------------------------------------------------
// Kernel A: three LinearOutputStacks. 4 rows/block, 512 threads,
// row-half split (rows 0-1 / 2-3). grid (256,3) = 768 blocks (3/CU).
// ------------------------------------------------------------------

__device__ __forceinline__ void ln4(float (*buf)[256], float* mrow, float* rrow)
{
    const int tid = threadIdx.x;
    const int lane = tid & 63, wv = tid >> 6;
    if (wv < 4) {                                  // wave wv reduces row wv
        float s = 0.f, s2 = 0.f;
        #pragma unroll
        for (int j = 0; j < 4; j++) {
            float v = buf[wv][lane + 64*j];
            s += v; s2 += v*v;
        }
        #pragma unroll
        for (int o = 32; o > 0; o >>= 1) {
            s  += __shfl_xor(s,  o, 64);
            s2 += __shfl_xor(s2, o, 64);
        }
        if (lane == 0) {
            float m   = s * (1.f/256.f);
            float var = s2 * (1.f/256.f) - m*m;
            mrow[wv] = m;
            rrow[wv] = rsqrtf(var + 1e-5f);
        }
    }
    __syncthreads();
    #pragma unroll
    for (int idx = tid; idx < 1024; idx += 512) {
        int r = idx >> 8, cc = idx & 255;
        buf[r][cc] = (buf[r][cc] - mrow[r]) * rrow[r];
    }
    __syncthreads();
}

// KDIM -> 256 matmul + bias + leaky_relu(0.2), 2 rows per thread
template<int KDIM>
__device__ __forceinline__ void mmv2(const float (*in)[KDIM],
                                     const float* __restrict__ W,
                                     const float* __restrict__ bias,
                                     float (*outb)[256])
{
    const int tid = threadIdx.x;
    const int c  = tid & 255;
    const int r0 = (tid >> 8) * 2;
    float acc[2] = {0.f, 0.f};
    const float* Wp = W + c;
    for (int l16 = 0; l16 < KDIM; l16 += 16) {
        float wbuf[16];
        #pragma unroll
        for (int j = 0; j < 16; j++) wbuf[j] = Wp[(size_t)(l16 + j)*256];
        #pragma unroll
        for (int q = 0; q < 4; q++) {
            f32x4 iq[2];
            #pragma unroll
            for (int r = 0; r < 2; r++) iq[r] = *(const f32x4*)&in[r0 + r][l16 + q*4];
            #pragma unroll
            for (int jj = 0; jj < 4; jj++)
                #pragma unroll
                for (int r = 0; r < 2; r++)
                    acc[r] = fmaf(iq[r][jj], wbuf[q*4 + jj], acc[r]);
        }
    }
    const float bb = bias[c];
    #pragma unroll
    for (int r = 0; r < 2; r++) {
        float v = acc[r] + bb;
        outb[r0 + r][c] = (v >= 0.f) ? v : 0.2f*v;
    }
}

__global__ __launch_bounds__(512) void mlp_kernel(
    const float* __restrict__ latents,
    const float* __restrict__ Win,  const float* __restrict__ b_in,
    const float* __restrict__ Wh,   const float* __restrict__ b_h,
    const float* __restrict__ Wout, const float* __restrict__ b_out,
    float* __restrict__ out3)
{
    __shared__ float bufA[4][128];
    __shared__ float bufB[4][256];
    __shared__ float bufC[4][256];
    __shared__ float mrow[4], rrow[4];

    const int tid  = threadIdx.x;
    const int s    = blockIdx.y;
    const int row0 = blockIdx.x * 4;
    const int c    = tid & 255;
    const int r0   = (tid >> 8) * 2;

    {
        int r = tid >> 7, l = tid & 127;           // 512 = 4*128 exactly
        bufA[r][l] = latents[(size_t)(row0 + r)*128 + l];
    }
    __syncthreads();

    mmv2<128>(bufA, Win + (size_t)s*128*256, b_in + s*256, bufB);
    __syncthreads();
    ln4(bufB, mrow, rrow);

    mmv2<256>(bufB, Wh + ((size_t)s*2 + 0)*256*256, b_h + (s*2 + 0)*256, bufC);
    __syncthreads();
    ln4(bufC, mrow, rrow);

    mmv2<256>(bufC, Wh + ((size_t)s*2 + 1)*256*256, b_h + (s*2 + 1)*256, bufB);
    __syncthreads();
    ln4(bufB, mrow, rrow);

    // output layer: 256 -> 257 (+bias), raw
    {
        float acc[2] = {0.f, 0.f};
        const float* Wp = Wout + (size_t)s*256*257 + c;
        for (int l16 = 0; l16 < 256; l16 += 16) {
            float wbuf[16];
            #pragma unroll
            for (int j = 0; j < 16; j++) wbuf[j] = Wp[(size_t)(l16 + j)*257];
            #pragma unroll
            for (int q = 0; q < 4; q++) {
                f32x4 iq[2];
                #pragma unroll
                for (int r = 0; r < 2; r++) iq[r] = *(const f32x4*)&bufB[r0 + r][l16 + q*4];
                #pragma unroll
                for (int jj = 0; jj < 4; jj++)
                    #pragma unroll
                    for (int r = 0; r < 2; r++)
                        acc[r] = fmaf(iq[r][jj], wbuf[q*4 + jj], acc[r]);
            }
        }
        float bb = b_out[s*257 + c];
        #pragma unroll
        for (int r = 0; r < 2; r++)
            out3[((size_t)s*1024 + row0 + r0 + r)*257 + c] = acc[r] + bb;

        // column 256 (one thread per row)
        if (tid < 4) {
            const int r = tid;
            float a = 0.f;
            const float* Wp2 = Wout + (size_t)s*256*257 + 256;
            for (int l = 0; l < 256; ++l)
                a = fmaf(bufB[r][l], Wp2[(size_t)l*257], a);
            out3[((size_t)s*1024 + row0 + r)*257 + 256] = a + b_out[s*257 + 256];
        }
    }
}

// ------------------------------------------------------------------
// K1: pack the quarter iDFT basis (k-mirror + w-mirror + parity split).
// Source cols w = 0..127 only; kappa = k2/2+1 in [1,128].
// tile = ks*8 + wv;  wv -> wg = wv>>1 (32-col group), p = wv&1 (parity).
// 64 tiles x 1 KB = 64 KB.
// ------------------------------------------------------------------
__global__ __launch_bounds__(256) void tpack_init(unsigned short* __restrict__ tp)
{
    int g = blockIdx.x * 256 + threadIdx.x;      // 64*64 = 4096 threads exactly
    int tile = g >> 6, l = g & 63;
    int ks = tile >> 3;                          // 0..7
    int wv = tile & 7;
    int wg = wv >> 1, p = wv & 1;
    u16x8 v;
    #pragma unroll
    for (int j = 0; j < 8; ++j) {
        int k2 = ks*32 + ((l >> 4) << 3) + j;    // < 256
        int kap = (k2 >> 1) + 1;                 // 1..128
        int w  = wg*32 + 2*(l & 15) + p;         // < 128
        int m  = (kap * w) & 511;                // exact angle reduction
        float ang = (float)m * (PI_F / 256.f);
        float sn, cn; sincosf(ang, &sn, &cn);
        v[j] = f2bf((k2 & 1) ? sn : cn);
    }
    *(u16x8*)(tp + (size_t)g * 8) = v;
}

// ------------------------------------------------------------------
// K2: full-row fused scan + quarter-basis MFMA iDFT + Hann/OLA.
// grid 1024, block 512 (8 waves), __launch_bounds__(512,4): 2 blocks/CU.
// Base = round-17.  NEW: all bf16 packing uses v_cvt_pk_bf16_f32
// (1 instr vs ~7/14 for the manual RNE path) in scan-consumer writes
// and the P/Q combine pass.
// ------------------------------------------------------------------
__global__ __launch_bounds__(512, 4) void synth_row(
    const float* __restrict__ out3,
    const float* __restrict__ phase0_u,
    const float* __restrict__ noise_u,
    const unsigned short* __restrict__ tpack,
    float* __restrict__ out)
{
    __shared__ __align__(16) unsigned int lds_u[16896];   // 67,584 B union
    __shared__ float a0s[64];
    __shared__ float a256s[64];
    __shared__ float pbuf[8][260];                        // 8,320 B
    __shared__ float xs128[64];
    __shared__ float xs384[64];

    unsigned int* abtP = lds_u;                  // [64][132] u32 (P -> R_even)
    unsigned int* abtQ = lds_u + 64*132;         // [64][132] u32 (Q -> R_odd)
    float*        xbf  = (float*)lds_u;          // [32][516] f32

    const int tid = threadIdx.x;
    const int row = blockIdx.x;
    const int b   = row >> 9;
    const int e   = row & 511;

    const float inv = 0.04419417382415922f;      // 1/sqrt(512)

    // ---- producer init (tid <= 256): phase recurrence only ----
    float pr = 0.f, dith_ = 0.f, gdd = 0.f;
    if (tid <= 256) {
        float dpre = out3[((size_t)2*1024 + row)*257 + tid];
        dith_ = sigm(dpre);
        float gd = (float)tid * (1.f/512.f);
        gdd = gd - 0.5f*dith_;                   // pr += fma(dith, nz, gdd)
        pr  = phase0_u[(size_t)row*257 + tid] - 0.5f;
    }
    // thread 256: Nyquist-bin evaluation state
    float m2 = 0.f, res2_ = 0.f;
    if (tid == 256) {
        float i2 = out3[((size_t)0*1024 + row)*257 + 256];
        float r2 = out3[((size_t)1*1024 + row)*257 + 256];
        res2_ = 0.5f + 0.4995f * sigm(r2);
        m2    = inv * i2;
    }

    // ---- consumer init (all threads): bin kc, frames j0..j0+3 ----
    const int kc = tid & 255;
    const int j0 = (tid >> 8) * 4;               // 0 or 4
    float m_base, rp1, rp2, rp3, res8;
    float bsgn = -1.f;
    unsigned int* tgt = abtP;                    // kc==0 never writes tgt
    {
        float ini  = out3[((size_t)0*1024 + row)*257 + kc];
        float rpre = out3[((size_t)1*1024 + row)*257 + kc];
        float res  = 0.5f + 0.4995f * sigm(rpre);
        float cs   = (kc == 0 ? 1.f : 2.f) * inv;
        rp1 = res;
        rp2 = res * res;
        rp3 = rp2 * res;
        float res4 = rp2 * rp2;
        res8 = res4 * res4;
        m_base = cs * ini;
        if (j0 == 4) m_base *= res4;
        if (kc >= 129)     { tgt = abtQ + (255 - kc); bsgn = 1.f; }
        else if (kc >= 1)  { tgt = abtP + (kc - 1); }
    }

    const float* nrow = noise_u + ((size_t)b*128*512 + e)*257;
    const size_t nstride = (size_t)512*257;

    // OLA constants for col w = tid (threads < 256)
    float h1 = 0.f, h2 = 0.f;
    {
        float c0 = __builtin_amdgcn_cosf((float)tid * (1.f/512.f));
        h1 = 0.5f - 0.5f*c0;                     // hann[tid]
        h2 = 0.5f + 0.5f*c0;                     // hann[tid+256]
    }
    const float sgn = (tid & 1) ? -1.f : 1.f;    // (-1)^w
    float tail = 0.f;

    const int l  = tid & 63;
    const int wv = tid >> 6;                     // 0..7: one 16-src-col tile
    const int m0 = l & 15;
    const int ac = l >> 4;
    const int wsrc = (wv >> 1)*32 + 2*m0 + (wv & 1);   // source col 0..127
    const int c1 = wsrc;                         // x[w]
    const int c2 = wsrc + 256;                   // x[w+256]
    const int c3 = 256 - wsrc;                   // x[256-w]
    const int c4 = 512 - wsrc;                   // x[512-w] (invalid at w=0)
    const bool c4ok = (wsrc != 0);
    const int4* abtP4 = (const int4*)abtP;       // row stride 33 int4
    const int4* abtQ4 = (const int4*)abtQ;
    const int4* abtR4 = (wv & 1) ? abtQ4 : abtP4;   // parity-selected R
    const int4* Tp    = (const int4*)tpack;
    const unsigned int S   = 0x80008000u;
    const unsigned int B31 = 0x80000000u;

    for (int sweep = 0; sweep < 2; ++sweep) {
        const int F0 = sweep * 64;

        // ---- phase 1: producer/consumer scan, 8 groups of 8 frames ----
        for (int g = 0; g < 8; ++g) {
            if (tid <= 256) {
                float nzb[8];
                #pragma unroll
                for (int j = 0; j < 8; ++j) {
                    int t = F0 + g*8 + j;
                    nzb[j] = (t >= 1) ? __builtin_nontemporal_load(
                                            &nrow[(size_t)t*nstride + tid]) : 0.5f;
                }
                #pragma unroll
                for (int j = 0; j < 8; ++j) {
                    int t = F0 + g*8 + j;
                    if (t >= 1) pr += fmaf(dith_, nzb[j], gdd);
                    pbuf[j][tid] = pr;
                    if (tid == 256) {            // Nyquist: cos only
                        if (t >= 1) m2 *= res2_;
                        float fr = pr - floorf(pr);
                        a256s[g*8 + j] = m2 * __builtin_amdgcn_cosf(fr);
                    }
                }
            } else if (g == 0 && tid >= 448) {
                // zero abtQ kappa=128 column (clobbered by xbf each sweep)
                abtQ[(tid - 448)*132 + 127] = 0;
            }
            __syncthreads();

            // consumers: all 512 threads, 4 (bin,frame) items each
            {
                const int fb = g*8 + j0;
                float mv[4];
                mv[0] = m_base;
                mv[1] = m_base * rp1;
                mv[2] = m_base * rp2;
                mv[3] = m_base * rp3;
                #pragma unroll
                for (int q = 0; q < 4; ++q) {
                    float p  = pbuf[j0 + q][kc];
                    float fr = p - floorf(p);
                    float sn = __builtin_amdgcn_sinf(fr);
                    float cn = __builtin_amdgcn_cosf(fr);
                    float a  = mv[q] * cn;
                    if (kc == 0) {
                        a0s[fb + q] = a;
                    } else {
                        float bv = bsgn * mv[q] * sn;
                        tgt[(fb + q)*132] = pk_bf16(a, bv);
                    }
                }
                m_base *= res8;
            }
            __syncthreads();
        }

        // ---- phase 1.5: P/Q combine (in place): P<-P+Q, Q<-P-Q ----
        {
            #pragma unroll
            for (int i = 0; i < 16; ++i) {
                int idx = tid + i*512;           // 0..8191
                int f  = idx >> 7, ki = idx & 127;
                int o  = f*132 + ki;
                unsigned int up = abtP[o];
                unsigned int uq = abtQ[o];
                float aP = bf_lo(up), bP = bf_hi(up);
                float aQ = bf_lo(uq), bQ = bf_hi(uq);
                abtP[o] = pk_bf16(aP + aQ, bP + bQ);
                abtQ[o] = pk_bf16(aP - aQ, bP - bQ);
            }
        }
        __syncthreads();

        // ---- phase 2: MFMA  M=64, N=128 src cols x 4 mirror variants ----
        f32x4 acc1[4], acc2[4], acc3[4], acc4[4];
        #pragma unroll
        for (int mt = 0; mt < 4; ++mt) {
            acc1[mt] = (f32x4){0.f, 0.f, 0.f, 0.f};
            acc2[mt] = (f32x4){0.f, 0.f, 0.f, 0.f};
            acc3[mt] = (f32x4){0.f, 0.f, 0.f, 0.f};
            acc4[mt] = (f32x4){0.f, 0.f, 0.f, 0.f};
        }
        {
            const int r0g = m0*33 + ac;
            for (int ks = 0; ks < 8; ++ks) {
                int4 bi = Tp[(size_t)((ks*8 + wv) << 6) + l];
                bf16x8 B = *(bf16x8*)&bi;
                #pragma unroll
                for (int mt = 0; mt < 4; ++mt) {
                    int4 t = abtR4[r0g + mt*528 + ks*4];
                    acc1[mt] = __builtin_amdgcn_mfma_f32_16x16x32_bf16(*(bf16x8*)&t, B, acc1[mt], 0, 0, 0);
                    t.x ^= S;   t.z ^= S;                              // v2: flip odd kappa
                    acc2[mt] = __builtin_amdgcn_mfma_f32_16x16x32_bf16(*(bf16x8*)&t, B, acc2[mt], 0, 0, 0);
                    t.x ^= B31; t.y ^= B31; t.z ^= B31; t.w ^= B31;    // v3
                    acc3[mt] = __builtin_amdgcn_mfma_f32_16x16x32_bf16(*(bf16x8*)&t, B, acc3[mt], 0, 0, 0);
                    t.x ^= S;   t.z ^= S;                              // v4: b negated
                    acc4[mt] = __builtin_amdgcn_mfma_f32_16x16x32_bf16(*(bf16x8*)&t, B, acc4[mt], 0, 0, 0);
                }
            }
        }

        // ---- phase 2.5: specials x[128], x[384] from combined E coeffs ----
        {
            const int f8 = tid >> 3;             // frame 0..63
            const int i8 = tid & 7;              // kappa chunk
            float s128 = 0.f, s384 = 0.f;
            #pragma unroll
            for (int q = 0; q < 16; ++q) {
                int ki = i8*16 + q;              // kappa = ki+1
                unsigned int ue = abtP[f8*132 + ki];
                if ((q + 1) & 1) {               // kappa odd: sin terms
                    float sg = ((q + 1) & 2) ? -1.f : 1.f;
                    float bsum = bf_hi(ue);
                    s128 += sg * bsum;
                    s384 -= sg * bsum;
                } else {                         // kappa even: cos terms
                    float sg = ((q + 1) & 2) ? -1.f : 1.f;
                    float asum = bf_lo(ue);
                    s128 += sg * asum;
                    s384 += sg * asum;
                }
            }
            #pragma unroll
            for (int o = 1; o < 8; o <<= 1) {
                s128 += __shfl_xor(s128, o, 64);
                s384 += __shfl_xor(s384, o, 64);
            }
            if (i8 == 0) { xs128[f8] = s128; xs384[f8] = s384; }
        }
        __syncthreads();   // abt reads done; xbf may overwrite

        // ---- phase 3: two 32-frame halves: acc -> xbf -> Hann+OLA ----
        #pragma unroll
        for (int h = 0; h < 2; ++h) {
            #pragma unroll
            for (int mt2 = 0; mt2 < 2; ++mt2) {
                int mtg = 2*h + mt2;
                #pragma unroll
                for (int r = 0; r < 4; ++r) {
                    int f_loc = mt2*16 + ac*4 + r;
                    float* xr = &xbf[f_loc*516];
                    xr[c1] = acc1[mtg][r];
                    xr[c2] = acc2[mtg][r];
                    xr[c3] = acc3[mtg][r];
                    if (c4ok) xr[c4] = acc4[mtg][r];
                }
            }
            if (tid < 32) {
                xbf[tid*516 + 128] = xs128[h*32 + tid];
                xbf[tid*516 + 384] = xs384[h*32 + tid];
            }
            __syncthreads();
            if (tid < 256) {
                float* orow = out + (size_t)row*32768 + (size_t)(F0 + h*32)*256 + tid;
                #pragma unroll
                for (int f = 0; f < 32; ++f) {
                    int hf = h*32 + f;
                    float s  = a0s[hf] + sgn * a256s[hf];
                    float x1 = xbf[f*516 + tid] + s;
                    float x2 = xbf[f*516 + tid + 256] + s;
                    float v  = fmaf(x1, h1, tail);
                    tail = x2 * h2;
                    __builtin_nontemporal_store(v, &orow[f*256]);
                }
            }
            __syncthreads();   // xbf reads done before next write / next abt
        }
    }
}

// ------------------------------------------------------------------

extern "C" void kernel_launch(void* const* d_in, const int* in_sizes, int n_in,
                              void* d_out, int out_size, void* d_ws, size_t ws_size,
                              hipStream_t stream)
{
    const float* latents  = (const float*)d_in[0];
    const float* phase0_u = (const float*)d_in[1];
    const float* noise_u  = (const float*)d_in[2];
    const float* Win      = (const float*)d_in[3];
    const float* b_in     = (const float*)d_in[4];
    const float* Wh       = (const float*)d_in[5];
    const float* b_h      = (const float*)d_in[6];
    const float* Wout     = (const float*)d_in[7];
    const float* b_out    = (const float*)d_in[8];

    unsigned char* ws = (unsigned char*)d_ws;
    float*          out3  = (float*)(ws + OUT3_OFF);
    unsigned short* tpack = (unsigned short*)(ws + TPACK_OFF);
    float*          out   = (float*)d_out;

    dim3 gA(256, 3);
    mlp_kernel<<<gA, 512, 0, stream>>>(latents, Win, b_in, Wh, b_h, Wout, b_out, out3);
    tpack_init<<<16, 256, 0, stream>>>(tpack);
    synth_row<<<1024, 512, 0, stream>>>(out3, phase0_u, noise_u, tpack, out);
}

// Round 19
// 165.960 us; speedup vs baseline: 3.6115x; 1.0171x over previous
//
#include <hip/hip_runtime.h>
#include <hip/hip_bf16.h>

#define PI_F 3.14159265358979323846f

typedef short  bf16x8 __attribute__((ext_vector_type(8)));
typedef unsigned short u16x8 __attribute__((ext_vector_type(8)));
typedef float  f32x4  __attribute__((ext_vector_type(4)));

// ---- ws layout (bytes) ----
#define OUT3_OFF  0                       // [3][1024][257] f32 = 3,158,016 B
#define TPACK_OFF 3158016                 // [64 tiles][64][8] bf16 = 65,536 B
#define WPACK_OFF (3158016 + 65536)       // 1344 tile-pairs x 2 KB = 2,752,512 B

static __device__ __forceinline__ unsigned short f2bf(float x) {
    unsigned int u = __float_as_uint(x);
    unsigned int r = (u + 0x7fffu + ((u >> 16) & 1u)) >> 16;   // RNE
    return (unsigned short)r;
}

// pack two f32 -> one u32 of 2 bf16 (lo = a, hi = b) in ONE instruction
static __device__ __forceinline__ unsigned int pk_bf16(float a, float b) {
    unsigned int r;
    asm("v_cvt_pk_bf16_f32 %0, %1, %2" : "=v"(r) : "v"(a), "v"(b));
    return r;
}

static __device__ __forceinline__ float sigm(float x) {
    return 1.f / (1.f + expf(-x));
}

static __device__ __forceinline__ float bf_lo(unsigned int u) {
    return __uint_as_float(u << 16);
}
static __device__ __forceinline__ float bf_hi(unsigned int u) {
    return __uint_as_float(u & 0xffff0000u);
}

// ------------------------------------------------------------------
// wpack: pre-split all MLP weights into bf16 hi/lo B-fragment tiles.
// Per stack s: L0 (K=128): tiles 0..63; L1: 64..191; L2: 192..319;
// L3 (Wout cols 0..255): 320..447.  Global tile t = s*448 + lt.
// Tile-pair layout: hi tile at slot 2t, lo at 2t+1 (512 bf16 each).
// B-frag: lane l elem j = W[k = ks*32+(l>>4)*8+j][n = nt*16+(l&15)].
// ------------------------------------------------------------------
__global__ __launch_bounds__(256) void wpack(
    const float* __restrict__ Win, const float* __restrict__ Wh,
    const float* __restrict__ Wout, unsigned short* __restrict__ wp)
{
    int g = blockIdx.x * 256 + threadIdx.x;     // 1344*64 = 86016 exactly
    int t = g >> 6, l = g & 63;
    int s = t / 448, lt = t % 448;
    int layer, base;
    if (lt < 64)       { layer = 0; base = 0;   }
    else if (lt < 192) { layer = 1; base = 64;  }
    else if (lt < 320) { layer = 2; base = 192; }
    else               { layer = 3; base = 320; }
    int local = lt - base, ks = local >> 4, nt = local & 15;

    u16x8 hv, lv;
    #pragma unroll
    for (int j = 0; j < 8; ++j) {
        int k = ks*32 + ((l >> 4) << 3) + j;
        int n = nt*16 + (l & 15);
        float w;
        if (layer == 0)      w = Win[(size_t)s*32768 + k*256 + n];
        else if (layer == 1) w = Wh[((size_t)s*2 + 0)*65536 + k*256 + n];
        else if (layer == 2) w = Wh[((size_t)s*2 + 1)*65536 + k*256 + n];
        else                 w = Wout[(size_t)s*65792 + k*257 + n];
        unsigned int ph = pk_bf16(w, 0.f);
        float fh = bf_lo(ph);
        hv[j] = (unsigned short)(ph & 0xffffu);
        lv[j] = (unsigned short)(pk_bf16(w - fh, 0.f) & 0xffffu);
    }
    *(u16x8*)(wp + (size_t)(t*2    )*512 + l*8) = hv;
    *(u16x8*)(wp + (size_t)(t*2 + 1)*512 + l*8) = lv;
}

// ------------------------------------------------------------------
// mlp_mfma: three LinearOutputStacks via split-bf16 MFMA.
// grid (16, 3): 64 rows x one stack per block; 512 threads (8 waves).
// Y = Xh*Wh + Xh*Wl + Xl*Wh  (rel err ~2^-16 ~ fp32).
// Activations: LDS hi/lo bf16 rows, A-frag stride 33 int4 (proven layout).
// LN/lrelu epilogues in fp32 (xs staging), final layer -> out3 direct.
// ------------------------------------------------------------------
__global__ __launch_bounds__(512) void mlp_mfma(
    const float* __restrict__ latents,
    const float* __restrict__ b_in, const float* __restrict__ b_h,
    const float* __restrict__ b_out, const float* __restrict__ Wout,
    const unsigned short* __restrict__ wp,
    float* __restrict__ out3)
{
    __shared__ float xs[64*260];                 // 66,560 B fp32 staging
    __shared__ unsigned int xh[64*132];          // 33,792 B bf16-hi pairs
    __shared__ unsigned int xl[64*132];          // 33,792 B bf16-lo pairs
    __shared__ float mrow[64], rrow[64];

    const int tid  = threadIdx.x;
    const int s    = blockIdx.y;
    const int row0 = blockIdx.x * 64;
    const int l  = tid & 63;
    const int wv = tid >> 6;                     // 0..7: 32-col slice
    const int m0 = l & 15;
    const int ac = l >> 4;

    const int4* Wp4 = (const int4*)wp;
    const int4* xh4 = (const int4*)xh;           // row stride 33 int4
    const int4* xl4 = (const int4*)xl;

    // ---- load + split latents (K=128): 4096 k-pairs ----
    #pragma unroll
    for (int i = 0; i < 8; ++i) {
        int idx = tid + i*512;
        int r = idx >> 6, kp = idx & 63;
        const float* lp = latents + (size_t)(row0 + r)*128 + 2*kp;
        float x0 = lp[0], x1 = lp[1];
        unsigned int u = pk_bf16(x0, x1);
        xh[r*132 + kp] = u;
        xl[r*132 + kp] = pk_bf16(x0 - bf_lo(u), x1 - bf_hi(u));
    }
    __syncthreads();

    for (int L = 0; L < 4; ++L) {
        const int kt    = (L == 0) ? 4 : 8;
        const int tbase = s*448 + ((L == 0) ? 0 : (L == 1) ? 64 : (L == 2) ? 192 : 320);

        f32x4 acc[4][2];
        #pragma unroll
        for (int mt = 0; mt < 4; ++mt) {
            acc[mt][0] = (f32x4){0.f, 0.f, 0.f, 0.f};
            acc[mt][1] = (f32x4){0.f, 0.f, 0.f, 0.f};
        }

        for (int ks = 0; ks < kt; ++ks) {
            const int t0 = tbase + ks*16 + wv*2;
            int4 bh0 = Wp4[(size_t)(t0*2    )*64 + l];
            int4 bl0 = Wp4[(size_t)(t0*2 + 1)*64 + l];
            int4 bh1 = Wp4[(size_t)(t0*2 + 2)*64 + l];
            int4 bl1 = Wp4[(size_t)(t0*2 + 3)*64 + l];
            bf16x8 BH0 = *(bf16x8*)&bh0, BL0 = *(bf16x8*)&bl0;
            bf16x8 BH1 = *(bf16x8*)&bh1, BL1 = *(bf16x8*)&bl1;
            #pragma unroll
            for (int mt = 0; mt < 4; ++mt) {
                int4 ah = xh4[(m0 + 16*mt)*33 + ks*4 + ac];
                int4 al = xl4[(m0 + 16*mt)*33 + ks*4 + ac];
                bf16x8 AH = *(bf16x8*)&ah, AL = *(bf16x8*)&al;
                acc[mt][0] = __builtin_amdgcn_mfma_f32_16x16x32_bf16(AH, BH0, acc[mt][0], 0, 0, 0);
                acc[mt][0] = __builtin_amdgcn_mfma_f32_16x16x32_bf16(AH, BL0, acc[mt][0], 0, 0, 0);
                acc[mt][0] = __builtin_amdgcn_mfma_f32_16x16x32_bf16(AL, BH0, acc[mt][0], 0, 0, 0);
                acc[mt][1] = __builtin_amdgcn_mfma_f32_16x16x32_bf16(AH, BH1, acc[mt][1], 0, 0, 0);
                acc[mt][1] = __builtin_amdgcn_mfma_f32_16x16x32_bf16(AH, BL1, acc[mt][1], 0, 0, 0);
                acc[mt][1] = __builtin_amdgcn_mfma_f32_16x16x32_bf16(AL, BH1, acc[mt][1], 0, 0, 0);
            }
        }

        if (L < 3) {
            // bias + leaky_relu -> xs
            const float* bias = (L == 0) ? (b_in + s*256) : (b_h + (s*2 + (L-1))*256);
            const float bb0 = bias[wv*32 + m0];
            const float bb1 = bias[wv*32 + 16 + m0];
            #pragma unroll
            for (int mt = 0; mt < 4; ++mt)
                #pragma unroll
                for (int r = 0; r < 4; ++r) {
                    int row = mt*16 + ac*4 + r;
                    float v0 = acc[mt][0][r] + bb0;
                    float v1 = acc[mt][1][r] + bb1;
                    v0 = (v0 >= 0.f) ? v0 : 0.2f*v0;
                    v1 = (v1 >= 0.f) ? v1 : 0.2f*v1;
                    xs[row*260 + wv*32 + m0]      = v0;
                    xs[row*260 + wv*32 + 16 + m0] = v1;
                }
            __syncthreads();

            // LN stats: wave wv reduces rows wv*8 .. wv*8+7
            #pragma unroll
            for (int i = 0; i < 8; ++i) {
                int row = wv*8 + i;
                float s1 = 0.f, s2 = 0.f;
                #pragma unroll
                for (int j = 0; j < 4; ++j) {
                    float v = xs[row*260 + l + 64*j];
                    s1 += v; s2 += v*v;
                }
                #pragma unroll
                for (int o = 32; o > 0; o >>= 1) {
                    s1 += __shfl_xor(s1, o, 64);
                    s2 += __shfl_xor(s2, o, 64);
                }
                if (l == 0) {
                    float m   = s1 * (1.f/256.f);
                    float var = s2 * (1.f/256.f) - m*m;
                    mrow[row] = m;
                    rrow[row] = rsqrtf(var + 1e-5f);
                }
            }
            __syncthreads();

            // normalize + split -> xh/xl (8192 k-pairs)
            #pragma unroll
            for (int i = 0; i < 16; ++i) {
                int idx = tid + i*512;
                int r = idx >> 7, kp = idx & 127;
                float mm = mrow[r], rr = rrow[r];
                float u = (xs[r*260 + 2*kp    ] - mm) * rr;
                float v = (xs[r*260 + 2*kp + 1] - mm) * rr;
                unsigned int uh = pk_bf16(u, v);
                xh[r*132 + kp] = uh;
                xl[r*132 + kp] = pk_bf16(u - bf_lo(uh), v - bf_hi(uh));
            }
            __syncthreads();
        } else {
            // L3: bias + direct store to out3 (cols 0..255)
            const float* bo = b_out + s*257;
            #pragma unroll
            for (int mt = 0; mt < 4; ++mt)
                #pragma unroll
                for (int r = 0; r < 4; ++r) {
                    int row = mt*16 + ac*4 + r;
                    float* op = out3 + ((size_t)s*1024 + row0 + row)*257;
                    op[wv*32 + m0]      = acc[mt][0][r] + bo[wv*32 + m0];
                    op[wv*32 + 16 + m0] = acc[mt][1][r] + bo[wv*32 + 16 + m0];
                }
            // col 256: 8 threads per row over normalized L2 activations
            {
                int r  = tid >> 3;
                int c8 = tid & 7;
                float mm = mrow[r], rr = rrow[r];
                float p = 0.f;
                const float* w2 = Wout + (size_t)s*65792 + 256;
                #pragma unroll
                for (int j = 0; j < 32; ++j) {
                    int cc = c8*32 + j;
                    p = fmaf((xs[r*260 + cc] - mm) * rr, w2[(size_t)cc*257], p);
                }
                p += __shfl_xor(p, 1, 64);
                p += __shfl_xor(p, 2, 64);
                p += __shfl_xor(p, 4, 64);
                if (c8 == 0)
                    out3[((size_t)s*1024 + row0 + r)*257 + 256] = p + b_out[s*257 + 256];
            }
        }
    }
}

// ------------------------------------------------------------------
// K1: pack the quarter iDFT basis (unchanged from round 18)
// ------------------------------------------------------------------
__global__ __launch_bounds__(256) void tpack_init(unsigned short* __restrict__ tp)
{
    int g = blockIdx.x * 256 + threadIdx.x;      // 64*64 = 4096 threads exactly
    int tile = g >> 6, l = g & 63;
    int ks = tile >> 3;                          // 0..7
    int wv = tile & 7;
    int wg = wv >> 1, p = wv & 1;
    u16x8 v;
    #pragma unroll
    for (int j = 0; j < 8; ++j) {
        int k2 = ks*32 + ((l >> 4) << 3) + j;    // < 256
        int kap = (k2 >> 1) + 1;                 // 1..128
        int w  = wg*32 + 2*(l & 15) + p;         // < 128
        int m  = (kap * w) & 511;                // exact angle reduction
        float ang = (float)m * (PI_F / 256.f);
        float sn, cn; sincosf(ang, &sn, &cn);
        v[j] = f2bf((k2 & 1) ? sn : cn);
    }
    *(u16x8*)(tp + (size_t)g * 8) = v;
}

// ------------------------------------------------------------------
// K2: full-row fused scan + quarter-basis MFMA iDFT + Hann/OLA.
// (byte-identical to round 18 — best verified synth)
// ------------------------------------------------------------------
__global__ __launch_bounds__(512, 4) void synth_row(
    const float* __restrict__ out3,
    const float* __restrict__ phase0_u,
    const float* __restrict__ noise_u,
    const unsigned short* __restrict__ tpack,
    float* __restrict__ out)
{
    __shared__ __align__(16) unsigned int lds_u[16896];   // 67,584 B union
    __shared__ float a0s[64];
    __shared__ float a256s[64];
    __shared__ float pbuf[8][260];                        // 8,320 B
    __shared__ float xs128[64];
    __shared__ float xs384[64];

    unsigned int* abtP = lds_u;                  // [64][132] u32 (P -> R_even)
    unsigned int* abtQ = lds_u + 64*132;         // [64][132] u32 (Q -> R_odd)
    float*        xbf  = (float*)lds_u;          // [32][516] f32

    const int tid = threadIdx.x;
    const int row = blockIdx.x;
    const int b   = row >> 9;
    const int e   = row & 511;

    const float inv = 0.04419417382415922f;      // 1/sqrt(512)

    // ---- producer init (tid <= 256): phase recurrence only ----
    float pr = 0.f, dith_ = 0.f, gdd = 0.f;
    if (tid <= 256) {
        float dpre = out3[((size_t)2*1024 + row)*257 + tid];
        dith_ = sigm(dpre);
        float gd = (float)tid * (1.f/512.f);
        gdd = gd - 0.5f*dith_;                   // pr += fma(dith, nz, gdd)
        pr  = phase0_u[(size_t)row*257 + tid] - 0.5f;
    }
    // thread 256: Nyquist-bin evaluation state
    float m2 = 0.f, res2_ = 0.f;
    if (tid == 256) {
        float i2 = out3[((size_t)0*1024 + row)*257 + 256];
        float r2 = out3[((size_t)1*1024 + row)*257 + 256];
        res2_ = 0.5f + 0.4995f * sigm(r2);
        m2    = inv * i2;
    }

    // ---- consumer init (all threads): bin kc, frames j0..j0+3 ----
    const int kc = tid & 255;
    const int j0 = (tid >> 8) * 4;               // 0 or 4
    float m_base, rp1, rp2, rp3, res8;
    float bsgn = -1.f;
    unsigned int* tgt = abtP;                    // kc==0 never writes tgt
    {
        float ini  = out3[((size_t)0*1024 + row)*257 + kc];
        float rpre = out3[((size_t)1*1024 + row)*257 + kc];
        float res  = 0.5f + 0.4995f * sigm(rpre);
        float cs   = (kc == 0 ? 1.f : 2.f) * inv;
        rp1 = res;
        rp2 = res * res;
        rp3 = rp2 * res;
        float res4 = rp2 * rp2;
        res8 = res4 * res4;
        m_base = cs * ini;
        if (j0 == 4) m_base *= res4;
        if (kc >= 129)     { tgt = abtQ + (255 - kc); bsgn = 1.f; }
        else if (kc >= 1)  { tgt = abtP + (kc - 1); }
    }

    const float* nrow = noise_u + ((size_t)b*128*512 + e)*257;
    const size_t nstride = (size_t)512*257;

    // OLA constants for col w = tid (threads < 256)
    float h1 = 0.f, h2 = 0.f;
    {
        float c0 = __builtin_amdgcn_cosf((float)tid * (1.f/512.f));
        h1 = 0.5f - 0.5f*c0;                     // hann[tid]
        h2 = 0.5f + 0.5f*c0;                     // hann[tid+256]
    }
    const float sgn = (tid & 1) ? -1.f : 1.f;    // (-1)^w
    float tail = 0.f;

    const int l  = tid & 63;
    const int wv = tid >> 6;                     // 0..7: one 16-src-col tile
    const int m0 = l & 15;
    const int ac = l >> 4;
    const int wsrc = (wv >> 1)*32 + 2*m0 + (wv & 1);   // source col 0..127
    const int c1 = wsrc;                         // x[w]
    const int c2 = wsrc + 256;                   // x[w+256]
    const int c3 = 256 - wsrc;                   // x[256-w]
    const int c4 = 512 - wsrc;                   // x[512-w] (invalid at w=0)
    const bool c4ok = (wsrc != 0);
    const int4* abtP4 = (const int4*)abtP;       // row stride 33 int4
    const int4* abtQ4 = (const int4*)abtQ;
    const int4* abtR4 = (wv & 1) ? abtQ4 : abtP4;   // parity-selected R
    const int4* Tp    = (const int4*)tpack;
    const unsigned int S   = 0x80008000u;
    const unsigned int B31 = 0x80000000u;

    for (int sweep = 0; sweep < 2; ++sweep) {
        const int F0 = sweep * 64;

        // ---- phase 1: producer/consumer scan, 8 groups of 8 frames ----
        for (int g = 0; g < 8; ++g) {
            if (tid <= 256) {
                float nzb[8];
                #pragma unroll
                for (int j = 0; j < 8; ++j) {
                    int t = F0 + g*8 + j;
                    nzb[j] = (t >= 1) ? __builtin_nontemporal_load(
                                            &nrow[(size_t)t*nstride + tid]) : 0.5f;
                }
                #pragma unroll
                for (int j = 0; j < 8; ++j) {
                    int t = F0 + g*8 + j;
                    if (t >= 1) pr += fmaf(dith_, nzb[j], gdd);
                    pbuf[j][tid] = pr;
                    if (tid == 256) {            // Nyquist: cos only
                        if (t >= 1) m2 *= res2_;
                        float fr = pr - floorf(pr);
                        a256s[g*8 + j] = m2 * __builtin_amdgcn_cosf(fr);
                    }
                }
            } else if (g == 0 && tid >= 448) {
                // zero abtQ kappa=128 column (clobbered by xbf each sweep)
                abtQ[(tid - 448)*132 + 127] = 0;
            }
            __syncthreads();

            // consumers: all 512 threads, 4 (bin,frame) items each
            {
                const int fb = g*8 + j0;
                float mv[4];
                mv[0] = m_base;
                mv[1] = m_base * rp1;
                mv[2] = m_base * rp2;
                mv[3] = m_base * rp3;
                #pragma unroll
                for (int q = 0; q < 4; ++q) {
                    float p  = pbuf[j0 + q][kc];
                    float fr = p - floorf(p);
                    float sn = __builtin_amdgcn_sinf(fr);
                    float cn = __builtin_amdgcn_cosf(fr);
                    float a  = mv[q] * cn;
                    if (kc == 0) {
                        a0s[fb + q] = a;
                    } else {
                        float bv = bsgn * mv[q] * sn;
                        tgt[(fb + q)*132] = pk_bf16(a, bv);
                    }
                }
                m_base *= res8;
            }
            __syncthreads();
        }

        // ---- phase 1.5: P/Q combine (in place): P<-P+Q, Q<-P-Q ----
        {
            #pragma unroll
            for (int i = 0; i < 16; ++i) {
                int idx = tid + i*512;           // 0..8191
                int f  = idx >> 7, ki = idx & 127;
                int o  = f*132 + ki;
                unsigned int up = abtP[o];
                unsigned int uq = abtQ[o];
                float aP = bf_lo(up), bP = bf_hi(up);
                float aQ = bf_lo(uq), bQ = bf_hi(uq);
                abtP[o] = pk_bf16(aP + aQ, bP + bQ);
                abtQ[o] = pk_bf16(aP - aQ, bP - bQ);
            }
        }
        __syncthreads();

        // ---- phase 2: MFMA  M=64, N=128 src cols x 4 mirror variants ----
        f32x4 acc1[4], acc2[4], acc3[4], acc4[4];
        #pragma unroll
        for (int mt = 0; mt < 4; ++mt) {
            acc1[mt] = (f32x4){0.f, 0.f, 0.f, 0.f};
            acc2[mt] = (f32x4){0.f, 0.f, 0.f, 0.f};
            acc3[mt] = (f32x4){0.f, 0.f, 0.f, 0.f};
            acc4[mt] = (f32x4){0.f, 0.f, 0.f, 0.f};
        }
        {
            const int r0g = m0*33 + ac;
            for (int ks = 0; ks < 8; ++ks) {
                int4 bi = Tp[(size_t)((ks*8 + wv) << 6) + l];
                bf16x8 B = *(bf16x8*)&bi;
                #pragma unroll
                for (int mt = 0; mt < 4; ++mt) {
                    int4 t = abtR4[r0g + mt*528 + ks*4];
                    acc1[mt] = __builtin_amdgcn_mfma_f32_16x16x32_bf16(*(bf16x8*)&t, B, acc1[mt], 0, 0, 0);
                    t.x ^= S;   t.z ^= S;                              // v2: flip odd kappa
                    acc2[mt] = __builtin_amdgcn_mfma_f32_16x16x32_bf16(*(bf16x8*)&t, B, acc2[mt], 0, 0, 0);
                    t.x ^= B31; t.y ^= B31; t.z ^= B31; t.w ^= B31;    // v3
                    acc3[mt] = __builtin_amdgcn_mfma_f32_16x16x32_bf16(*(bf16x8*)&t, B, acc3[mt], 0, 0, 0);
                    t.x ^= S;   t.z ^= S;                              // v4: b negated
                    acc4[mt] = __builtin_amdgcn_mfma_f32_16x16x32_bf16(*(bf16x8*)&t, B, acc4[mt], 0, 0, 0);
                }
            }
        }

        // ---- phase 2.5: specials x[128], x[384] from combined E coeffs ----
        {
            const int f8 = tid >> 3;             // frame 0..63
            const int i8 = tid & 7;              // kappa chunk
            float s128 = 0.f, s384 = 0.f;
            #pragma unroll
            for (int q = 0; q < 16; ++q) {
                int ki = i8*16 + q;              // kappa = ki+1
                unsigned int ue = abtP[f8*132 + ki];
                if ((q + 1) & 1) {               // kappa odd: sin terms
                    float sg = ((q + 1) & 2) ? -1.f : 1.f;
                    float bsum = bf_hi(ue);
                    s128 += sg * bsum;
                    s384 -= sg * bsum;
                } else {                         // kappa even: cos terms
                    float sg = ((q + 1) & 2) ? -1.f : 1.f;
                    float asum = bf_lo(ue);
                    s128 += sg * asum;
                    s384 += sg * asum;
                }
            }
            #pragma unroll
            for (int o = 1; o < 8; o <<= 1) {
                s128 += __shfl_xor(s128, o, 64);
                s384 += __shfl_xor(s384, o, 64);
            }
            if (i8 == 0) { xs128[f8] = s128; xs384[f8] = s384; }
        }
        __syncthreads();   // abt reads done; xbf may overwrite

        // ---- phase 3: two 32-frame halves: acc -> xbf -> Hann+OLA ----
        #pragma unroll
        for (int h = 0; h < 2; ++h) {
            #pragma unroll
            for (int mt2 = 0; mt2 < 2; ++mt2) {
                int mtg = 2*h + mt2;
                #pragma unroll
                for (int r = 0; r < 4; ++r) {
                    int f_loc = mt2*16 + ac*4 + r;
                    float* xr = &xbf[f_loc*516];
                    xr[c1] = acc1[mtg][r];
                    xr[c2] = acc2[mtg][r];
                    xr[c3] = acc3[mtg][r];
                    if (c4ok) xr[c4] = acc4[mtg][r];
                }
            }
            if (tid < 32) {
                xbf[tid*516 + 128] = xs128[h*32 + tid];
                xbf[tid*516 + 384] = xs384[h*32 + tid];
            }
            __syncthreads();
            if (tid < 256) {
                float* orow = out + (size_t)row*32768 + (size_t)(F0 + h*32)*256 + tid;
                #pragma unroll
                for (int f = 0; f < 32; ++f) {
                    int hf = h*32 + f;
                    float s  = a0s[hf] + sgn * a256s[hf];
                    float x1 = xbf[f*516 + tid] + s;
                    float x2 = xbf[f*516 + tid + 256] + s;
                    float v  = fmaf(x1, h1, tail);
                    tail = x2 * h2;
                    __builtin_nontemporal_store(v, &orow[f*256]);
                }
            }
            __syncthreads();   // xbf reads done before next write / next abt
        }
    }
}

// ------------------------------------------------------------------

extern "C" void kernel_launch(void* const* d_in, const int* in_sizes, int n_in,
                              void* d_out, int out_size, void* d_ws, size_t ws_size,
                              hipStream_t stream)
{
    const float* latents  = (const float*)d_in[0];
    const float* phase0_u = (const float*)d_in[1];
    const float* noise_u  = (const float*)d_in[2];
    const float* Win      = (const float*)d_in[3];
    const float* b_in     = (const float*)d_in[4];
    const float* Wh       = (const float*)d_in[5];
    const float* b_h      = (const float*)d_in[6];
    const float* Wout     = (const float*)d_in[7];
    const float* b_out    = (const float*)d_in[8];

    unsigned char* ws = (unsigned char*)d_ws;
    float*          out3  = (float*)(ws + OUT3_OFF);
    unsigned short* tpack = (unsigned short*)(ws + TPACK_OFF);
    unsigned short* wp    = (unsigned short*)(ws + WPACK_OFF);
    float*          out   = (float*)d_out;

    wpack<<<336, 256, 0, stream>>>(Win, Wh, Wout, wp);
    dim3 gM(16, 3);
    mlp_mfma<<<gM, 512, 0, stream>>>(latents, b_in, b_h, b_out, Wout, wp, out3);
    tpack_init<<<16, 256, 0, stream>>>(tpack);
    synth_row<<<1024, 512, 0, stream>>>(out3, phase0_u, noise_u, tpack, out);
}